// Round 5
// baseline (884.086 us; speedup 1.0000x reference)
//
#include <hip/hip_runtime.h>

// Problem constants
#define BB 4
#define TT 2048
#define CC 2048
#define NHEAD 16
#define DH 128
#define MM (BB * TT)          // 8192 rows
#define N3 (3 * CC)           // 6144
#define LD3 6144

typedef unsigned short u16;
typedef __attribute__((ext_vector_type(8))) short short8;
typedef __attribute__((ext_vector_type(4))) float f32x4;

__device__ __forceinline__ u16 f2bf(float f) {
  unsigned u = __float_as_uint(f);
  u += 0x7fffu + ((u >> 16) & 1u);      // RNE
  return (u16)(u >> 16);
}
__device__ __forceinline__ float bf2f(u16 h) {
  return __uint_as_float(((unsigned)h) << 16);
}

__device__ __forceinline__ void gload_lds16(const void* g, void* l) {
  __builtin_amdgcn_global_load_lds((const __attribute__((address_space(1))) void*)g,
                                   (__attribute__((address_space(3))) void*)l, 16, 0, 0);
}

__device__ __forceinline__ f32x4 mfma16(short8 a, short8 b, f32x4 c) {
  return __builtin_amdgcn_mfma_f32_16x16x32_bf16(a, b, c, 0, 0, 0);
}

// ---------------------------------------------------------------- convert x
__global__ void convert_x_kernel(const float* __restrict__ x, u16* __restrict__ xb) {
  const int total = (MM * CC) / 4;
  const float4* xv = (const float4*)x;
  ushort4* ov = (ushort4*)xb;
  for (int i = blockIdx.x * blockDim.x + threadIdx.x; i < total; i += gridDim.x * blockDim.x) {
    float4 v = xv[i];
    ushort4 o;
    o.x = f2bf(v.x); o.y = f2bf(v.y); o.z = f2bf(v.z); o.w = f2bf(v.w);
    ov[i] = o;
  }
}

// ------------------------------------------- transpose + convert W -> W^T bf16
__global__ void transpose_bf16_kernel(const float* __restrict__ W, u16* __restrict__ Wt,
                                      int rows, int cols) {
  __shared__ float tile[32][33];
  const int n0 = blockIdx.x * 32, k0 = blockIdx.y * 32;
  const int tx = threadIdx.x, ty = threadIdx.y;   // (32, 8)
  #pragma unroll
  for (int i = 0; i < 4; ++i)
    tile[ty + 8 * i][tx] = W[(size_t)(k0 + ty + 8 * i) * cols + n0 + tx];
  __syncthreads();
  #pragma unroll
  for (int i = 0; i < 4; ++i)
    Wt[(size_t)(n0 + ty + 8 * i) * rows + k0 + tx] = f2bf(tile[tx][ty + 8 * i]);
}

// ---------------------------------------------------------------- rope table
__global__ void rope_table_kernel(float2* __restrict__ tab) {
  int idx = blockIdx.x * 256 + threadIdx.x;     // T*64 entries
  int t = idx >> 6, f = idx & 63;
  float freq = expf(-0.14391156831f * (float)f);   // 10000^(-f/64)
  float ang = (float)t * freq;
  float s, c;
  sincosf(ang, &s, &c);
  tab[idx] = make_float2(c, s);
}

// ------------------------------------------------------- rope apply (q and k)
__global__ void rope_apply_kernel(u16* __restrict__ qkv, const float2* __restrict__ tab) {
  int idx = blockIdx.x * 256 + threadIdx.x;   // 2^24 = 2 * M * 16 * 64
  int f = idx & 63;
  int h = (idx >> 6) & 15;
  int m = (idx >> 10) & 8191;
  int which = idx >> 23;                      // 0 = q, 1 = k
  int t = m & (TT - 1);
  u16* p = qkv + (size_t)m * LD3 + which * CC + h * DH + f;
  float2 cs = tab[(t << 6) + f];
  float x1 = bf2f(p[0]), x2 = bf2f(p[64]);
  float o1 = x1 * cs.x - x2 * cs.y;
  float o2 = x2 * cs.x + x1 * cs.y;
  if (which == 0) { o1 *= 0.08838834764831845f; o2 *= 0.08838834764831845f; }
  p[0] = f2bf(o1);
  p[64] = f2bf(o2);
}

// ------------------------------------------------------------------- GEMM
// C[m][n] = sum_k A[m][k] * Bt[n][k];  A: M x K bf16, Bt: N x K bf16.
// 128x128 tile, 4 waves, BK=32, global_load_lds staging (m97 structure, R3-exact).
__global__ __launch_bounds__(256) void gemm_bt_128(const u16* __restrict__ A,
                                                   const u16* __restrict__ Bt,
                                                   void* __restrict__ Cout,
                                                   int K, int ldc, int out_bf16) {
  __shared__ __align__(16) u16 As[128 * 32];
  __shared__ __align__(16) u16 Bs[128 * 32];
  const int tid = threadIdx.x;
  const int wid = tid >> 6, lane = tid & 63;
  const int l15 = lane & 15, g = lane >> 4;
  const int row0 = blockIdx.y * 128, col0 = blockIdx.x * 128;
  const int wr = (wid >> 1) * 64, wc = (wid & 1) * 64;
  f32x4 acc[4][4];
  #pragma unroll
  for (int m = 0; m < 4; ++m)
    #pragma unroll
    for (int n = 0; n < 4; ++n)
      acc[m][n] = (f32x4){0.f, 0.f, 0.f, 0.f};

  for (int k0 = 0; k0 < K; k0 += 32) {
    #pragma unroll
    for (int c = 0; c < 2; ++c) {
      int chunk = c * 256 + tid;          // 0..511 ; 8-bf16 chunks of the 128x32 tile
      int r = chunk >> 2, co = chunk & 3;
      gload_lds16(A + (size_t)(row0 + r) * K + k0 + co * 8, &As[(c * 256 + wid * 64) * 8]);
      gload_lds16(Bt + (size_t)(col0 + r) * K + k0 + co * 8, &Bs[(c * 256 + wid * 64) * 8]);
    }
    asm volatile("s_waitcnt vmcnt(0)" ::: "memory");
    __syncthreads();
    short8 af[4], bfr[4];
    #pragma unroll
    for (int m = 0; m < 4; ++m)
      af[m] = *(const short8*)&As[(wr + m * 16 + l15) * 32 + g * 8];
    #pragma unroll
    for (int n = 0; n < 4; ++n)
      bfr[n] = *(const short8*)&Bs[(wc + n * 16 + l15) * 32 + g * 8];
    #pragma unroll
    for (int m = 0; m < 4; ++m)
      #pragma unroll
      for (int n = 0; n < 4; ++n)
        acc[m][n] = mfma16(af[m], bfr[n], acc[m][n]);
    __syncthreads();
  }

  if (out_bf16) {
    u16* Cb = (u16*)Cout;
    #pragma unroll
    for (int m = 0; m < 4; ++m)
      #pragma unroll
      for (int n = 0; n < 4; ++n) {
        int row = row0 + wr + m * 16 + 4 * g;
        int col = col0 + wc + n * 16 + l15;
        #pragma unroll
        for (int j = 0; j < 4; ++j)
          Cb[(size_t)(row + j) * ldc + col] = f2bf(acc[m][n][j]);
      }
  } else {
    float* Cf = (float*)Cout;
    #pragma unroll
    for (int m = 0; m < 4; ++m)
      #pragma unroll
      for (int n = 0; n < 4; ++n) {
        int row = row0 + wr + m * 16 + 4 * g;
        int col = col0 + wc + n * 16 + l15;
        #pragma unroll
        for (int j = 0; j < 4; ++j)
          Cf[(size_t)(row + j) * ldc + col] = acc[m][n][j];
      }
  }
}

// ---------------------------------------------------------------- attention
// QBLK=128 (each wave owns 32 q-rows as 2 fragments): doubles K/V reuse per
// staged byte (the R4 diagnosis: cache-BW-bound on K/V re-reads) and halves
// barrier count per unit work. P round-trips through Ks[cur] (dead after QK)
// with G4 XOR swizzle; one extra barrier separates all-waves-QK from P-writes.
#define QBLK 128
#define KBLK 64
#define PADV 72

__global__ __launch_bounds__(256) void attn_kernel(const u16* __restrict__ qkv,
                                                   u16* __restrict__ y) {
  __shared__ __align__(16) u16 Ks[2][KBLK * 128];   // K tile (swizzled) / P buffer
  __shared__ __align__(16) u16 Vt[2][DH * PADV];    // V^T [d][kv], padded
  const int tid = threadIdx.x;
  const int wid = tid >> 6, lane = tid & 63;
  const int l15 = lane & 15, g = lane >> 4;
  const int qt0 = blockIdx.x * QBLK;
  const int b = blockIdx.y >> 4, h = blockIdx.y & 15;
  const size_t rb = (size_t)b * TT;
  const int vk0 = (tid & 15) * 4, vd0 = (tid >> 4) * 8;   // V-staging assignment

  // ---- Q fragments straight from global (one-time; rows 12KB apart)
  short8 qf[2][4];
  {
    const u16* qbase = qkv + (rb + qt0 + wid * 32 + l15) * LD3 + h * DH;
    #pragma unroll
    for (int f = 0; f < 2; ++f)
      #pragma unroll
      for (int kk = 0; kk < 4; ++kk)
        qf[f][kk] = *(const short8*)(qbase + f * 16 * LD3 + kk * 32 + g * 8);
  }

  // ---- prologue: stage K(tile0) -> Ks[0], V(tile0) -> Vt[0]
  {
    const u16* kbase = qkv + (rb)*LD3 + CC + h * DH;
    #pragma unroll
    for (int c = 0; c < 4; ++c) {
      int chunk = c * 256 + tid;
      int r = chunk >> 4, s = chunk & 15;
      gload_lds16(kbase + (size_t)r * LD3 + (size_t)((s ^ (r & 7)) * 8),
                  &Ks[0][(c * 256 + wid * 64) * 8]);
    }
    const u16* vg = qkv + (rb + vk0) * LD3 + 2 * CC + h * DH + vd0;
    short8 r0 = *(const short8*)vg;
    short8 r1 = *(const short8*)(vg + LD3);
    short8 r2 = *(const short8*)(vg + 2 * LD3);
    short8 r3 = *(const short8*)(vg + 3 * LD3);
    #pragma unroll
    for (int j = 0; j < 8; ++j) {
      ushort4 w;
      w.x = (u16)r0[j]; w.y = (u16)r1[j]; w.z = (u16)r2[j]; w.w = (u16)r3[j];
      *(ushort4*)&Vt[0][(vd0 + j) * PADV + vk0] = w;
    }
  }
  asm volatile("s_waitcnt vmcnt(0)" ::: "memory");
  __syncthreads();

  f32x4 o[2][8];
  float mrun[2][4], lrun[2][4];
  #pragma unroll
  for (int f = 0; f < 2; ++f) {
    #pragma unroll
    for (int nf = 0; nf < 8; ++nf) o[f][nf] = (f32x4){0.f, 0.f, 0.f, 0.f};
    #pragma unroll
    for (int j = 0; j < 4; ++j) { mrun[f][j] = -1e30f; lrun[f][j] = 0.f; }
  }

  const int nt = qt0 / KBLK + 2;           // kv tiles (last two intersect diagonal)
  for (int it = 0; it < nt; ++it) {
    const int cur = it & 1, nxt = cur ^ 1;
    const bool havenext = (it + 1) < nt;
    short8 r0, r1, r2, r3;
    if (havenext) {
      const int kvn = (it + 1) * KBLK;
      const u16* kbase = qkv + (rb + kvn) * LD3 + CC + h * DH;
      #pragma unroll
      for (int c = 0; c < 4; ++c) {
        int chunk = c * 256 + tid;
        int r = chunk >> 4, s = chunk & 15;
        gload_lds16(kbase + (size_t)r * LD3 + (size_t)((s ^ (r & 7)) * 8),
                    &Ks[nxt][(c * 256 + wid * 64) * 8]);
      }
      const u16* vg = qkv + (rb + kvn + vk0) * LD3 + 2 * CC + h * DH + vd0;
      r0 = *(const short8*)vg;
      r1 = *(const short8*)(vg + LD3);
      r2 = *(const short8*)(vg + 2 * LD3);
      r3 = *(const short8*)(vg + 3 * LD3);
    }

    // ---- S = Q K^T from Ks[cur] (q pre-scaled by 1/sqrt(D))
    f32x4 s4[2][4];
    #pragma unroll
    for (int f = 0; f < 2; ++f)
      #pragma unroll
      for (int jf = 0; jf < 4; ++jf) s4[f][jf] = (f32x4){0.f, 0.f, 0.f, 0.f};
    #pragma unroll
    for (int jf = 0; jf < 4; ++jf) {
      int krow = jf * 16 + l15;
      #pragma unroll
      for (int kk = 0; kk < 4; ++kk) {
        short8 kf = *(const short8*)((const char*)Ks[cur] + krow * 256 +
                                     ((kk * 64 + g * 16) ^ ((l15 & 7) << 4)));
        s4[0][jf] = mfma16(qf[0][kk], kf, s4[0][jf]);
        s4[1][jf] = mfma16(qf[1][kk], kf, s4[1][jf]);
      }
    }
    // causal mask: last two tiles intersect the diagonal of this q-block
    if (it >= nt - 2) {
      const int kvb = it * KBLK - qt0;     // kv offset relative to q-block base
      #pragma unroll
      for (int f = 0; f < 2; ++f)
        #pragma unroll
        for (int jf = 0; jf < 4; ++jf)
          #pragma unroll
          for (int j = 0; j < 4; ++j)
            if (kvb + jf * 16 + l15 > wid * 32 + f * 16 + 4 * g + j)
              s4[f][jf][j] = -1e30f;
    }
    // ---- online softmax per fragment
    #pragma unroll
    for (int f = 0; f < 2; ++f) {
      float rmax[4], corr[4], rsum[4];
      #pragma unroll
      for (int j = 0; j < 4; ++j)
        rmax[j] = fmaxf(fmaxf(s4[f][0][j], s4[f][1][j]), fmaxf(s4[f][2][j], s4[f][3][j]));
      #pragma unroll
      for (int j = 0; j < 4; ++j) {
        rmax[j] = fmaxf(rmax[j], __shfl_xor(rmax[j], 1, 64));
        rmax[j] = fmaxf(rmax[j], __shfl_xor(rmax[j], 2, 64));
        rmax[j] = fmaxf(rmax[j], __shfl_xor(rmax[j], 4, 64));
        rmax[j] = fmaxf(rmax[j], __shfl_xor(rmax[j], 8, 64));
      }
      #pragma unroll
      for (int j = 0; j < 4; ++j) {
        float mn = fmaxf(mrun[f][j], rmax[j]);
        corr[j] = __expf(mrun[f][j] - mn);
        mrun[f][j] = mn;
      }
      #pragma unroll
      for (int jf = 0; jf < 4; ++jf)
        #pragma unroll
        for (int j = 0; j < 4; ++j)
          s4[f][jf][j] = __expf(s4[f][jf][j] - mrun[f][j]);
      #pragma unroll
      for (int j = 0; j < 4; ++j) {
        rsum[j] = (s4[f][0][j] + s4[f][1][j]) + (s4[f][2][j] + s4[f][3][j]);
        rsum[j] += __shfl_xor(rsum[j], 1, 64);
        rsum[j] += __shfl_xor(rsum[j], 2, 64);
        rsum[j] += __shfl_xor(rsum[j], 4, 64);
        rsum[j] += __shfl_xor(rsum[j], 8, 64);
        lrun[f][j] = lrun[f][j] * corr[j] + rsum[j];
      }
      #pragma unroll
      for (int nf = 0; nf < 8; ++nf)
        #pragma unroll
        for (int j = 0; j < 4; ++j)
          o[f][nf][j] *= corr[j];
    }

    // ---- all waves done reading K from Ks[cur]; reuse it as the P buffer
    __syncthreads();
    // P flat [128 q-rows][64 kv], G4 XOR swizzle: col ^= (row&7)<<3 (16B granule)
    {
      u16* Pb = (u16*)Ks[cur];
      #pragma unroll
      for (int f = 0; f < 2; ++f)
        #pragma unroll
        for (int jf = 0; jf < 4; ++jf)
          #pragma unroll
          for (int j = 0; j < 4; ++j) {
            int prow = wid * 32 + f * 16 + 4 * g + j;
            int pcol = (jf * 16 + l15) ^ (((4 * g + j) & 7) << 3);
            Pb[prow * 64 + pcol] = f2bf(s4[f][jf][j]);
          }
    }
    asm volatile("s_waitcnt lgkmcnt(0)" ::: "memory");
    __builtin_amdgcn_sched_barrier(0);
    short8 pf[2][2];
    #pragma unroll
    for (int f = 0; f < 2; ++f)
      #pragma unroll
      for (int kk = 0; kk < 2; ++kk)
        pf[f][kk] = *(const short8*)&((const u16*)Ks[cur])[
            (wid * 32 + f * 16 + l15) * 64 + ((kk * 32 + g * 8) ^ ((l15 & 7) << 3))];

    // ---- O += P V from Vt[cur] (vf read shared across both fragments)
    #pragma unroll
    for (int nf = 0; nf < 8; ++nf) {
      #pragma unroll
      for (int kk = 0; kk < 2; ++kk) {
        short8 vf = *(const short8*)&Vt[cur][(nf * 16 + l15) * PADV + kk * 32 + g * 8];
        o[0][nf] = mfma16(pf[0][kk], vf, o[0][nf]);
        o[1][nf] = mfma16(pf[1][kk], vf, o[1][nf]);
      }
    }

    // ---- late V write into the other buffer (global-load latency hidden)
    if (havenext) {
      #pragma unroll
      for (int j = 0; j < 8; ++j) {
        ushort4 w;
        w.x = (u16)r0[j]; w.y = (u16)r1[j]; w.z = (u16)r2[j]; w.w = (u16)r3[j];
        *(ushort4*)&Vt[nxt][(vd0 + j) * PADV + vk0] = w;
      }
    }
    asm volatile("s_waitcnt vmcnt(0)" ::: "memory");
    __syncthreads();
  }

  #pragma unroll
  for (int f = 0; f < 2; ++f) {
    float inv[4];
    #pragma unroll
    for (int j = 0; j < 4; ++j) inv[j] = 1.0f / lrun[f][j];
    #pragma unroll
    for (int nf = 0; nf < 8; ++nf)
      #pragma unroll
      for (int j = 0; j < 4; ++j)
        y[(rb + qt0 + wid * 32 + f * 16 + 4 * g + j) * CC + h * DH + nf * 16 + l15] =
            f2bf(o[f][nf][j] * inv[f == 0 ? j : j]);   // inv per f
  }
}

// ------------------------------------------------------------------ launch
// Workspace layout: non-aliased, 193 MB total.
extern "C" void kernel_launch(void* const* d_in, const int* in_sizes, int n_in,
                              void* d_out, int out_size, void* d_ws, size_t ws_size,
                              hipStream_t stream) {
  const float* x = (const float*)d_in[0];
  const float* Wqkv = (const float*)d_in[1];
  const float* Wproj = (const float*)d_in[2];
  char* ws = (char*)d_ws;
  u16* xb     = (u16*)(ws);                      // 32 MB
  u16* wqkvT  = (u16*)(ws + 33554432);           // 24 MB
  u16* wprojT = (u16*)(ws + 58720256);           // 8 MB
  u16* qkv    = (u16*)(ws + 67108864);           // 96 MB
  u16* y      = (u16*)(ws + 167772160);          // 32 MB
  float2* tab = (float2*)(ws + 201326592);       // 1 MB

  convert_x_kernel<<<4096, 256, 0, stream>>>(x, xb);
  transpose_bf16_kernel<<<dim3(192, 64), dim3(32, 8), 0, stream>>>(Wqkv, wqkvT, CC, N3);
  transpose_bf16_kernel<<<dim3(64, 64), dim3(32, 8), 0, stream>>>(Wproj, wprojT, CC, CC);
  rope_table_kernel<<<512, 256, 0, stream>>>(tab);
  gemm_bt_128<<<dim3(48, 64), 256, 0, stream>>>(xb, wqkvT, (void*)qkv, CC, LD3, 1);
  rope_apply_kernel<<<65536, 256, 0, stream>>>(qkv, tab);
  attn_kernel<<<dim3(16, 64), 256, 0, stream>>>(qkv, y);
  gemm_bt_128<<<dim3(16, 64), 256, 0, stream>>>(y, wprojT, d_out, CC, CC, 0);
}

// Round 6
// 733.117 us; speedup vs baseline: 1.2059x; 1.2059x over previous
//
#include <hip/hip_runtime.h>

// Problem constants
#define BB 4
#define TT 2048
#define CC 2048
#define NHEAD 16
#define DH 128
#define MM (BB * TT)          // 8192 rows
#define N3 (3 * CC)           // 6144
#define LD3 6144

typedef unsigned short u16;
typedef __attribute__((ext_vector_type(8))) short short8;
typedef __attribute__((ext_vector_type(4))) float f32x4;

__device__ __forceinline__ u16 f2bf(float f) {
  unsigned u = __float_as_uint(f);
  u += 0x7fffu + ((u >> 16) & 1u);      // RNE
  return (u16)(u >> 16);
}
__device__ __forceinline__ float bf2f(u16 h) {
  return __uint_as_float(((unsigned)h) << 16);
}

__device__ __forceinline__ void gload_lds16(const void* g, void* l) {
  __builtin_amdgcn_global_load_lds((const __attribute__((address_space(1))) void*)g,
                                   (__attribute__((address_space(3))) void*)l, 16, 0, 0);
}

__device__ __forceinline__ f32x4 mfma16(short8 a, short8 b, f32x4 c) {
  return __builtin_amdgcn_mfma_f32_16x16x32_bf16(a, b, c, 0, 0, 0);
}

// ---------------------------------------------------------------- convert x
__global__ void convert_x_kernel(const float* __restrict__ x, u16* __restrict__ xb) {
  const int total = (MM * CC) / 4;
  const float4* xv = (const float4*)x;
  ushort4* ov = (ushort4*)xb;
  for (int i = blockIdx.x * blockDim.x + threadIdx.x; i < total; i += gridDim.x * blockDim.x) {
    float4 v = xv[i];
    ushort4 o;
    o.x = f2bf(v.x); o.y = f2bf(v.y); o.z = f2bf(v.z); o.w = f2bf(v.w);
    ov[i] = o;
  }
}

// ------------------------------------------- transpose + convert W -> W^T bf16
__global__ void transpose_bf16_kernel(const float* __restrict__ W, u16* __restrict__ Wt,
                                      int rows, int cols) {
  __shared__ float tile[32][33];
  const int n0 = blockIdx.x * 32, k0 = blockIdx.y * 32;
  const int tx = threadIdx.x, ty = threadIdx.y;   // (32, 8)
  #pragma unroll
  for (int i = 0; i < 4; ++i)
    tile[ty + 8 * i][tx] = W[(size_t)(k0 + ty + 8 * i) * cols + n0 + tx];
  __syncthreads();
  #pragma unroll
  for (int i = 0; i < 4; ++i)
    Wt[(size_t)(n0 + ty + 8 * i) * rows + k0 + tx] = f2bf(tile[tx][ty + 8 * i]);
}

// ---------------------------------------------------------------- rope table
__global__ void rope_table_kernel(float2* __restrict__ tab) {
  int idx = blockIdx.x * 256 + threadIdx.x;     // T*64 entries
  int t = idx >> 6, f = idx & 63;
  float freq = expf(-0.14391156831f * (float)f);   // 10000^(-f/64)
  float ang = (float)t * freq;
  float s, c;
  sincosf(ang, &s, &c);
  tab[idx] = make_float2(c, s);
}

// ------------------------------------------------------- rope apply (q and k)
__global__ void rope_apply_kernel(u16* __restrict__ qkv, const float2* __restrict__ tab) {
  int idx = blockIdx.x * 256 + threadIdx.x;   // 2^24 = 2 * M * 16 * 64
  int f = idx & 63;
  int h = (idx >> 6) & 15;
  int m = (idx >> 10) & 8191;
  int which = idx >> 23;                      // 0 = q, 1 = k
  int t = m & (TT - 1);
  u16* p = qkv + (size_t)m * LD3 + which * CC + h * DH + f;
  float2 cs = tab[(t << 6) + f];
  float x1 = bf2f(p[0]), x2 = bf2f(p[64]);
  float o1 = x1 * cs.x - x2 * cs.y;
  float o2 = x2 * cs.x + x1 * cs.y;
  if (which == 0) { o1 *= 0.08838834764831845f; o2 *= 0.08838834764831845f; }
  p[0] = f2bf(o1);
  p[64] = f2bf(o2);
}

// ------------------------------------------------------------------- GEMM
// C[m][n] = sum_k A[m][k] * Bt[n][k];  A: M x K bf16, Bt: N x K bf16.
// 128x128 tile, 4 waves, BK=32, global_load_lds staging (m97 structure, R3-exact).
__global__ __launch_bounds__(256) void gemm_bt_128(const u16* __restrict__ A,
                                                   const u16* __restrict__ Bt,
                                                   void* __restrict__ Cout,
                                                   int K, int ldc, int out_bf16) {
  __shared__ __align__(16) u16 As[128 * 32];
  __shared__ __align__(16) u16 Bs[128 * 32];
  const int tid = threadIdx.x;
  const int wid = tid >> 6, lane = tid & 63;
  const int l15 = lane & 15, g = lane >> 4;
  const int row0 = blockIdx.y * 128, col0 = blockIdx.x * 128;
  const int wr = (wid >> 1) * 64, wc = (wid & 1) * 64;
  f32x4 acc[4][4];
  #pragma unroll
  for (int m = 0; m < 4; ++m)
    #pragma unroll
    for (int n = 0; n < 4; ++n)
      acc[m][n] = (f32x4){0.f, 0.f, 0.f, 0.f};

  for (int k0 = 0; k0 < K; k0 += 32) {
    #pragma unroll
    for (int c = 0; c < 2; ++c) {
      int chunk = c * 256 + tid;          // 0..511 ; 8-bf16 chunks of the 128x32 tile
      int r = chunk >> 2, co = chunk & 3;
      gload_lds16(A + (size_t)(row0 + r) * K + k0 + co * 8, &As[(c * 256 + wid * 64) * 8]);
      gload_lds16(Bt + (size_t)(col0 + r) * K + k0 + co * 8, &Bs[(c * 256 + wid * 64) * 8]);
    }
    asm volatile("s_waitcnt vmcnt(0)" ::: "memory");
    __syncthreads();
    short8 af[4], bfr[4];
    #pragma unroll
    for (int m = 0; m < 4; ++m)
      af[m] = *(const short8*)&As[(wr + m * 16 + l15) * 32 + g * 8];
    #pragma unroll
    for (int n = 0; n < 4; ++n)
      bfr[n] = *(const short8*)&Bs[(wc + n * 16 + l15) * 32 + g * 8];
    #pragma unroll
    for (int m = 0; m < 4; ++m)
      #pragma unroll
      for (int n = 0; n < 4; ++n)
        acc[m][n] = mfma16(af[m], bfr[n], acc[m][n]);
    __syncthreads();
  }

  if (out_bf16) {
    u16* Cb = (u16*)Cout;
    #pragma unroll
    for (int m = 0; m < 4; ++m)
      #pragma unroll
      for (int n = 0; n < 4; ++n) {
        int row = row0 + wr + m * 16 + 4 * g;
        int col = col0 + wc + n * 16 + l15;
        #pragma unroll
        for (int j = 0; j < 4; ++j)
          Cb[(size_t)(row + j) * ldc + col] = f2bf(acc[m][n][j]);
      }
  } else {
    float* Cf = (float*)Cout;
    #pragma unroll
    for (int m = 0; m < 4; ++m)
      #pragma unroll
      for (int n = 0; n < 4; ++n) {
        int row = row0 + wr + m * 16 + 4 * g;
        int col = col0 + wc + n * 16 + l15;
        #pragma unroll
        for (int j = 0; j < 4; ++j)
          Cf[(size_t)(row + j) * ldc + col] = acc[m][n][j];
      }
  }
}

// ---------------------------------------------------------------- attention
// QBLK=128, diagonal pairing: block pidx processes q-tiles {pidx, 15-pidx},
// so every block costs (2*pidx+2) + (32-2*pidx) = 34 iters — uniform. Grid
// 8x64 = 512 blocks = exactly 2 blocks/CU resident for the whole kernel
// (R5 diagnosis: triangular tail left the machine ~95% idle).
#define QBLK 128
#define KBLK 64
#define PADV 72

__global__ __launch_bounds__(256) void attn_kernel(const u16* __restrict__ qkv,
                                                   u16* __restrict__ y) {
  __shared__ __align__(16) u16 Ks[2][KBLK * 128];   // K tile (swizzled) / P buffer
  __shared__ __align__(16) u16 Vt[2][DH * PADV];    // V^T [d][kv], padded
  const int tid = threadIdx.x;
  const int wid = tid >> 6, lane = tid & 63;
  const int l15 = lane & 15, g = lane >> 4;
  const int b = blockIdx.y >> 4, h = blockIdx.y & 15;
  const size_t rb = (size_t)b * TT;
  const int vk0 = (tid & 15) * 4, vd0 = (tid >> 4) * 8;   // V-staging assignment

  for (int half = 0; half < 2; ++half) {
    const int qt0 = (half ? (15 - (int)blockIdx.x) : (int)blockIdx.x) * QBLK;

    // ---- Q fragments straight from global (one-time; rows 12KB apart)
    short8 qf[2][4];
    {
      const u16* qbase = qkv + (rb + qt0 + wid * 32 + l15) * LD3 + h * DH;
      #pragma unroll
      for (int f = 0; f < 2; ++f)
        #pragma unroll
        for (int kk = 0; kk < 4; ++kk)
          qf[f][kk] = *(const short8*)(qbase + f * 16 * LD3 + kk * 32 + g * 8);
    }

    // ---- prologue: stage K(tile0) -> Ks[0], V(tile0) -> Vt[0]
    // (previous half ended with vmcnt(0)+barrier, so buffers are reusable)
    {
      const u16* kbase = qkv + (rb)*LD3 + CC + h * DH;
      #pragma unroll
      for (int c = 0; c < 4; ++c) {
        int chunk = c * 256 + tid;
        int r = chunk >> 4, s = chunk & 15;
        gload_lds16(kbase + (size_t)r * LD3 + (size_t)((s ^ (r & 7)) * 8),
                    &Ks[0][(c * 256 + wid * 64) * 8]);
      }
      const u16* vg = qkv + (rb + vk0) * LD3 + 2 * CC + h * DH + vd0;
      short8 r0 = *(const short8*)vg;
      short8 r1 = *(const short8*)(vg + LD3);
      short8 r2 = *(const short8*)(vg + 2 * LD3);
      short8 r3 = *(const short8*)(vg + 3 * LD3);
      #pragma unroll
      for (int j = 0; j < 8; ++j) {
        ushort4 w;
        w.x = (u16)r0[j]; w.y = (u16)r1[j]; w.z = (u16)r2[j]; w.w = (u16)r3[j];
        *(ushort4*)&Vt[0][(vd0 + j) * PADV + vk0] = w;
      }
    }
    asm volatile("s_waitcnt vmcnt(0)" ::: "memory");
    __syncthreads();

    f32x4 o[2][8];
    float mrun[2][4], lrun[2][4];
    #pragma unroll
    for (int f = 0; f < 2; ++f) {
      #pragma unroll
      for (int nf = 0; nf < 8; ++nf) o[f][nf] = (f32x4){0.f, 0.f, 0.f, 0.f};
      #pragma unroll
      for (int j = 0; j < 4; ++j) { mrun[f][j] = -1e30f; lrun[f][j] = 0.f; }
    }

    const int nt = qt0 / KBLK + 2;         // kv tiles (last two intersect diagonal)
    for (int it = 0; it < nt; ++it) {
      const int cur = it & 1, nxt = cur ^ 1;
      const bool havenext = (it + 1) < nt;
      short8 r0, r1, r2, r3;
      if (havenext) {
        const int kvn = (it + 1) * KBLK;
        const u16* kbase = qkv + (rb + kvn) * LD3 + CC + h * DH;
        #pragma unroll
        for (int c = 0; c < 4; ++c) {
          int chunk = c * 256 + tid;
          int r = chunk >> 4, s = chunk & 15;
          gload_lds16(kbase + (size_t)r * LD3 + (size_t)((s ^ (r & 7)) * 8),
                      &Ks[nxt][(c * 256 + wid * 64) * 8]);
        }
        const u16* vg = qkv + (rb + kvn + vk0) * LD3 + 2 * CC + h * DH + vd0;
        r0 = *(const short8*)vg;
        r1 = *(const short8*)(vg + LD3);
        r2 = *(const short8*)(vg + 2 * LD3);
        r3 = *(const short8*)(vg + 3 * LD3);
      }

      // ---- S = Q K^T from Ks[cur] (q pre-scaled by 1/sqrt(D))
      f32x4 s4[2][4];
      #pragma unroll
      for (int f = 0; f < 2; ++f)
        #pragma unroll
        for (int jf = 0; jf < 4; ++jf) s4[f][jf] = (f32x4){0.f, 0.f, 0.f, 0.f};
      #pragma unroll
      for (int jf = 0; jf < 4; ++jf) {
        int krow = jf * 16 + l15;
        #pragma unroll
        for (int kk = 0; kk < 4; ++kk) {
          short8 kf = *(const short8*)((const char*)Ks[cur] + krow * 256 +
                                       ((kk * 64 + g * 16) ^ ((l15 & 7) << 4)));
          s4[0][jf] = mfma16(qf[0][kk], kf, s4[0][jf]);
          s4[1][jf] = mfma16(qf[1][kk], kf, s4[1][jf]);
        }
      }
      // causal mask: last two tiles intersect the diagonal of this q-block
      if (it >= nt - 2) {
        const int kvb = it * KBLK - qt0;   // kv offset relative to q-block base
        #pragma unroll
        for (int f = 0; f < 2; ++f)
          #pragma unroll
          for (int jf = 0; jf < 4; ++jf)
            #pragma unroll
            for (int j = 0; j < 4; ++j)
              if (kvb + jf * 16 + l15 > wid * 32 + f * 16 + 4 * g + j)
                s4[f][jf][j] = -1e30f;
      }
      // ---- online softmax per fragment
      #pragma unroll
      for (int f = 0; f < 2; ++f) {
        float rmax[4], corr[4], rsum[4];
        #pragma unroll
        for (int j = 0; j < 4; ++j)
          rmax[j] = fmaxf(fmaxf(s4[f][0][j], s4[f][1][j]), fmaxf(s4[f][2][j], s4[f][3][j]));
        #pragma unroll
        for (int j = 0; j < 4; ++j) {
          rmax[j] = fmaxf(rmax[j], __shfl_xor(rmax[j], 1, 64));
          rmax[j] = fmaxf(rmax[j], __shfl_xor(rmax[j], 2, 64));
          rmax[j] = fmaxf(rmax[j], __shfl_xor(rmax[j], 4, 64));
          rmax[j] = fmaxf(rmax[j], __shfl_xor(rmax[j], 8, 64));
        }
        #pragma unroll
        for (int j = 0; j < 4; ++j) {
          float mn = fmaxf(mrun[f][j], rmax[j]);
          corr[j] = __expf(mrun[f][j] - mn);
          mrun[f][j] = mn;
        }
        #pragma unroll
        for (int jf = 0; jf < 4; ++jf)
          #pragma unroll
          for (int j = 0; j < 4; ++j)
            s4[f][jf][j] = __expf(s4[f][jf][j] - mrun[f][j]);
        #pragma unroll
        for (int j = 0; j < 4; ++j) {
          rsum[j] = (s4[f][0][j] + s4[f][1][j]) + (s4[f][2][j] + s4[f][3][j]);
          rsum[j] += __shfl_xor(rsum[j], 1, 64);
          rsum[j] += __shfl_xor(rsum[j], 2, 64);
          rsum[j] += __shfl_xor(rsum[j], 4, 64);
          rsum[j] += __shfl_xor(rsum[j], 8, 64);
          lrun[f][j] = lrun[f][j] * corr[j] + rsum[j];
        }
        #pragma unroll
        for (int nf = 0; nf < 8; ++nf)
          #pragma unroll
          for (int j = 0; j < 4; ++j)
            o[f][nf][j] *= corr[j];
      }

      // ---- all waves done reading K from Ks[cur]; reuse it as the P buffer
      __syncthreads();
      // P flat [128 q-rows][64 kv], G4 XOR swizzle: col ^= (row&7)<<3
      {
        u16* Pb = (u16*)Ks[cur];
        #pragma unroll
        for (int f = 0; f < 2; ++f)
          #pragma unroll
          for (int jf = 0; jf < 4; ++jf)
            #pragma unroll
            for (int j = 0; j < 4; ++j) {
              int prow = wid * 32 + f * 16 + 4 * g + j;
              int pcol = (jf * 16 + l15) ^ (((4 * g + j) & 7) << 3);
              Pb[prow * 64 + pcol] = f2bf(s4[f][jf][j]);
            }
      }
      asm volatile("s_waitcnt lgkmcnt(0)" ::: "memory");
      __builtin_amdgcn_sched_barrier(0);
      short8 pf[2][2];
      #pragma unroll
      for (int f = 0; f < 2; ++f)
        #pragma unroll
        for (int kk = 0; kk < 2; ++kk)
          pf[f][kk] = *(const short8*)&((const u16*)Ks[cur])[
              (wid * 32 + f * 16 + l15) * 64 + ((kk * 32 + g * 8) ^ ((l15 & 7) << 3))];

      // ---- O += P V from Vt[cur] (vf read shared across both fragments)
      #pragma unroll
      for (int nf = 0; nf < 8; ++nf) {
        #pragma unroll
        for (int kk = 0; kk < 2; ++kk) {
          short8 vf = *(const short8*)&Vt[cur][(nf * 16 + l15) * PADV + kk * 32 + g * 8];
          o[0][nf] = mfma16(pf[0][kk], vf, o[0][nf]);
          o[1][nf] = mfma16(pf[1][kk], vf, o[1][nf]);
        }
      }

      // ---- late V write into the other buffer (global-load latency hidden)
      if (havenext) {
        #pragma unroll
        for (int j = 0; j < 8; ++j) {
          ushort4 w;
          w.x = (u16)r0[j]; w.y = (u16)r1[j]; w.z = (u16)r2[j]; w.w = (u16)r3[j];
          *(ushort4*)&Vt[nxt][(vd0 + j) * PADV + vk0] = w;
        }
      }
      asm volatile("s_waitcnt vmcnt(0)" ::: "memory");
      __syncthreads();
    }

    // ---- write back this q-tile
    #pragma unroll
    for (int f = 0; f < 2; ++f) {
      float inv[4];
      #pragma unroll
      for (int j = 0; j < 4; ++j) inv[j] = 1.0f / lrun[f][j];
      #pragma unroll
      for (int nf = 0; nf < 8; ++nf)
        #pragma unroll
        for (int j = 0; j < 4; ++j)
          y[(rb + qt0 + wid * 32 + f * 16 + 4 * g + j) * CC + h * DH + nf * 16 + l15] =
              f2bf(o[f][nf][j] * inv[j]);
    }
  }
}

// ------------------------------------------------------------------ launch
// Workspace layout: non-aliased, 193 MB total.
extern "C" void kernel_launch(void* const* d_in, const int* in_sizes, int n_in,
                              void* d_out, int out_size, void* d_ws, size_t ws_size,
                              hipStream_t stream) {
  const float* x = (const float*)d_in[0];
  const float* Wqkv = (const float*)d_in[1];
  const float* Wproj = (const float*)d_in[2];
  char* ws = (char*)d_ws;
  u16* xb     = (u16*)(ws);                      // 32 MB
  u16* wqkvT  = (u16*)(ws + 33554432);           // 24 MB
  u16* wprojT = (u16*)(ws + 58720256);           // 8 MB
  u16* qkv    = (u16*)(ws + 67108864);           // 96 MB
  u16* y      = (u16*)(ws + 167772160);          // 32 MB
  float2* tab = (float2*)(ws + 201326592);       // 1 MB

  convert_x_kernel<<<4096, 256, 0, stream>>>(x, xb);
  transpose_bf16_kernel<<<dim3(192, 64), dim3(32, 8), 0, stream>>>(Wqkv, wqkvT, CC, N3);
  transpose_bf16_kernel<<<dim3(64, 64), dim3(32, 8), 0, stream>>>(Wproj, wprojT, CC, CC);
  rope_table_kernel<<<512, 256, 0, stream>>>(tab);
  gemm_bt_128<<<dim3(48, 64), 256, 0, stream>>>(xb, wqkvT, (void*)qkv, CC, LD3, 1);
  rope_apply_kernel<<<65536, 256, 0, stream>>>(qkv, tab);
  attn_kernel<<<dim3(8, 64), 256, 0, stream>>>(qkv, y);
  gemm_bt_128<<<dim3(16, 64), 256, 0, stream>>>(y, wprojT, d_out, CC, CC, 0);
}

// Round 7
// 634.560 us; speedup vs baseline: 1.3932x; 1.1553x over previous
//
#include <hip/hip_runtime.h>

// Problem constants
#define BB 4
#define TT 2048
#define CC 2048
#define NHEAD 16
#define DH 128
#define MM (BB * TT)          // 8192 rows
#define N3 (3 * CC)           // 6144
#define LD3 6144

typedef unsigned short u16;
typedef __attribute__((ext_vector_type(8))) short short8;
typedef __attribute__((ext_vector_type(4))) float f32x4;

__device__ __forceinline__ u16 f2bf(float f) {
  unsigned u = __float_as_uint(f);
  u += 0x7fffu + ((u >> 16) & 1u);      // RNE
  return (u16)(u >> 16);
}
__device__ __forceinline__ float bf2f(u16 h) {
  return __uint_as_float(((unsigned)h) << 16);
}

__device__ __forceinline__ void gload_lds16(const void* g, void* l) {
  __builtin_amdgcn_global_load_lds((const __attribute__((address_space(1))) void*)g,
                                   (__attribute__((address_space(3))) void*)l, 16, 0, 0);
}

__device__ __forceinline__ f32x4 mfma16(short8 a, short8 b, f32x4 c) {
  return __builtin_amdgcn_mfma_f32_16x16x32_bf16(a, b, c, 0, 0, 0);
}

// ---------------------------------------------------------------- convert x
__global__ void convert_x_kernel(const float* __restrict__ x, u16* __restrict__ xb) {
  const int total = (MM * CC) / 4;
  const float4* xv = (const float4*)x;
  ushort4* ov = (ushort4*)xb;
  for (int i = blockIdx.x * blockDim.x + threadIdx.x; i < total; i += gridDim.x * blockDim.x) {
    float4 v = xv[i];
    ushort4 o;
    o.x = f2bf(v.x); o.y = f2bf(v.y); o.z = f2bf(v.z); o.w = f2bf(v.w);
    ov[i] = o;
  }
}

// ------------------------------------------- transpose + convert W -> W^T bf16
__global__ void transpose_bf16_kernel(const float* __restrict__ W, u16* __restrict__ Wt,
                                      int rows, int cols) {
  __shared__ float tile[32][33];
  const int n0 = blockIdx.x * 32, k0 = blockIdx.y * 32;
  const int tx = threadIdx.x, ty = threadIdx.y;   // (32, 8)
  #pragma unroll
  for (int i = 0; i < 4; ++i)
    tile[ty + 8 * i][tx] = W[(size_t)(k0 + ty + 8 * i) * cols + n0 + tx];
  __syncthreads();
  #pragma unroll
  for (int i = 0; i < 4; ++i)
    Wt[(size_t)(n0 + ty + 8 * i) * rows + k0 + tx] = f2bf(tile[tx][ty + 8 * i]);
}

// ---------------------------------------------------------------- rope table
__global__ void rope_table_kernel(float2* __restrict__ tab) {
  int idx = blockIdx.x * 256 + threadIdx.x;     // T*64 entries
  int t = idx >> 6, f = idx & 63;
  float freq = expf(-0.14391156831f * (float)f);   // 10000^(-f/64)
  float ang = (float)t * freq;
  float s, c;
  sincosf(ang, &s, &c);
  tab[idx] = make_float2(c, s);
}

// ------------------------------------------------------- rope apply (q and k)
__global__ void rope_apply_kernel(u16* __restrict__ qkv, const float2* __restrict__ tab) {
  int idx = blockIdx.x * 256 + threadIdx.x;   // 2^24 = 2 * M * 16 * 64
  int f = idx & 63;
  int h = (idx >> 6) & 15;
  int m = (idx >> 10) & 8191;
  int which = idx >> 23;                      // 0 = q, 1 = k
  int t = m & (TT - 1);
  u16* p = qkv + (size_t)m * LD3 + which * CC + h * DH + f;
  float2 cs = tab[(t << 6) + f];
  float x1 = bf2f(p[0]), x2 = bf2f(p[64]);
  float o1 = x1 * cs.x - x2 * cs.y;
  float o2 = x2 * cs.x + x1 * cs.y;
  if (which == 0) { o1 *= 0.08838834764831845f; o2 *= 0.08838834764831845f; }
  p[0] = f2bf(o1);
  p[64] = f2bf(o2);
}

// ------------------------------------------------------------------- GEMM
// C[m][n] = sum_k A[m][k] * Bt[n][k];  A: M x K bf16, Bt: N x K bf16.
// 128x128 tile, 4 waves, BK=32, global_load_lds staging (m97 structure, R3-exact).
__global__ __launch_bounds__(256) void gemm_bt_128(const u16* __restrict__ A,
                                                   const u16* __restrict__ Bt,
                                                   void* __restrict__ Cout,
                                                   int K, int ldc, int out_bf16) {
  __shared__ __align__(16) u16 As[128 * 32];
  __shared__ __align__(16) u16 Bs[128 * 32];
  const int tid = threadIdx.x;
  const int wid = tid >> 6, lane = tid & 63;
  const int l15 = lane & 15, g = lane >> 4;
  const int row0 = blockIdx.y * 128, col0 = blockIdx.x * 128;
  const int wr = (wid >> 1) * 64, wc = (wid & 1) * 64;
  f32x4 acc[4][4];
  #pragma unroll
  for (int m = 0; m < 4; ++m)
    #pragma unroll
    for (int n = 0; n < 4; ++n)
      acc[m][n] = (f32x4){0.f, 0.f, 0.f, 0.f};

  for (int k0 = 0; k0 < K; k0 += 32) {
    #pragma unroll
    for (int c = 0; c < 2; ++c) {
      int chunk = c * 256 + tid;          // 0..511 ; 8-bf16 chunks of the 128x32 tile
      int r = chunk >> 2, co = chunk & 3;
      gload_lds16(A + (size_t)(row0 + r) * K + k0 + co * 8, &As[(c * 256 + wid * 64) * 8]);
      gload_lds16(Bt + (size_t)(col0 + r) * K + k0 + co * 8, &Bs[(c * 256 + wid * 64) * 8]);
    }
    asm volatile("s_waitcnt vmcnt(0)" ::: "memory");
    __syncthreads();
    short8 af[4], bfr[4];
    #pragma unroll
    for (int m = 0; m < 4; ++m)
      af[m] = *(const short8*)&As[(wr + m * 16 + l15) * 32 + g * 8];
    #pragma unroll
    for (int n = 0; n < 4; ++n)
      bfr[n] = *(const short8*)&Bs[(wc + n * 16 + l15) * 32 + g * 8];
    #pragma unroll
    for (int m = 0; m < 4; ++m)
      #pragma unroll
      for (int n = 0; n < 4; ++n)
        acc[m][n] = mfma16(af[m], bfr[n], acc[m][n]);
    __syncthreads();
  }

  if (out_bf16) {
    u16* Cb = (u16*)Cout;
    #pragma unroll
    for (int m = 0; m < 4; ++m)
      #pragma unroll
      for (int n = 0; n < 4; ++n) {
        int row = row0 + wr + m * 16 + 4 * g;
        int col = col0 + wc + n * 16 + l15;
        #pragma unroll
        for (int j = 0; j < 4; ++j)
          Cb[(size_t)(row + j) * ldc + col] = f2bf(acc[m][n][j]);
      }
  } else {
    float* Cf = (float*)Cout;
    #pragma unroll
    for (int m = 0; m < 4; ++m)
      #pragma unroll
      for (int n = 0; n < 4; ++n) {
        int row = row0 + wr + m * 16 + 4 * g;
        int col = col0 + wc + n * 16 + l15;
        #pragma unroll
        for (int j = 0; j < 4; ++j)
          Cf[(size_t)(row + j) * ldc + col] = acc[m][n][j];
      }
  }
}

// ---------------------------------------------------------------- attention
// QBLK=128, diagonal pairing (uniform 34 iters/block), 512 blocks.
// R6 diagnosis: ~264 regs/wave (200 VGPR + 64 AGPR) -> only 1 wave/SIMD ->
// 1 block/CU; softmax VALU and MFMA serialize. This round: fit 2 waves/SIMD
// via __launch_bounds__(256,2) + short V-staging liveness (load V right
// before its LDS write instead of holding 16 regs across the whole tile;
// the co-resident block now provides the latency hiding via TLP).
#define QBLK 128
#define KBLK 64
#define PADV 72

__global__ __launch_bounds__(256, 2) void attn_kernel(const u16* __restrict__ qkv,
                                                      u16* __restrict__ y) {
  __shared__ __align__(16) u16 Ks[2][KBLK * 128];   // K tile (swizzled) / P buffer
  __shared__ __align__(16) u16 Vt[2][DH * PADV];    // V^T [d][kv], padded
  const int tid = threadIdx.x;
  const int wid = tid >> 6, lane = tid & 63;
  const int l15 = lane & 15, g = lane >> 4;
  const int b = blockIdx.y >> 4, h = blockIdx.y & 15;
  const size_t rb = (size_t)b * TT;
  const int vk0 = (tid & 15) * 4, vd0 = (tid >> 4) * 8;   // V-staging assignment

  for (int half = 0; half < 2; ++half) {
    const int qt0 = (half ? (15 - (int)blockIdx.x) : (int)blockIdx.x) * QBLK;

    // ---- Q fragments straight from global (one-time; rows 12KB apart)
    short8 qf[2][4];
    {
      const u16* qbase = qkv + (rb + qt0 + wid * 32 + l15) * LD3 + h * DH;
      #pragma unroll
      for (int f = 0; f < 2; ++f)
        #pragma unroll
        for (int kk = 0; kk < 4; ++kk)
          qf[f][kk] = *(const short8*)(qbase + f * 16 * LD3 + kk * 32 + g * 8);
    }

    // ---- prologue: stage K(tile0) -> Ks[0], V(tile0) -> Vt[0]
    {
      const u16* kbase = qkv + (rb)*LD3 + CC + h * DH;
      #pragma unroll
      for (int c = 0; c < 4; ++c) {
        int chunk = c * 256 + tid;
        int r = chunk >> 4, s = chunk & 15;
        gload_lds16(kbase + (size_t)r * LD3 + (size_t)((s ^ (r & 7)) * 8),
                    &Ks[0][(c * 256 + wid * 64) * 8]);
      }
      const u16* vg = qkv + (rb + vk0) * LD3 + 2 * CC + h * DH + vd0;
      short8 r0 = *(const short8*)vg;
      short8 r1 = *(const short8*)(vg + LD3);
      short8 r2 = *(const short8*)(vg + 2 * LD3);
      short8 r3 = *(const short8*)(vg + 3 * LD3);
      #pragma unroll
      for (int j = 0; j < 8; ++j) {
        ushort4 w;
        w.x = (u16)r0[j]; w.y = (u16)r1[j]; w.z = (u16)r2[j]; w.w = (u16)r3[j];
        *(ushort4*)&Vt[0][(vd0 + j) * PADV + vk0] = w;
      }
    }
    asm volatile("s_waitcnt vmcnt(0)" ::: "memory");
    __syncthreads();

    f32x4 o[2][8];
    float mrun[2][4], lrun[2][4];
    #pragma unroll
    for (int f = 0; f < 2; ++f) {
      #pragma unroll
      for (int nf = 0; nf < 8; ++nf) o[f][nf] = (f32x4){0.f, 0.f, 0.f, 0.f};
      #pragma unroll
      for (int j = 0; j < 4; ++j) { mrun[f][j] = -1e30f; lrun[f][j] = 0.f; }
    }

    const int nt = qt0 / KBLK + 2;         // kv tiles (last two intersect diagonal)
    for (int it = 0; it < nt; ++it) {
      const int cur = it & 1, nxt = cur ^ 1;
      const bool havenext = (it + 1) < nt;
      if (havenext) {
        const int kvn = (it + 1) * KBLK;
        const u16* kbase = qkv + (rb + kvn) * LD3 + CC + h * DH;
        #pragma unroll
        for (int c = 0; c < 4; ++c) {
          int chunk = c * 256 + tid;
          int r = chunk >> 4, s = chunk & 15;
          gload_lds16(kbase + (size_t)r * LD3 + (size_t)((s ^ (r & 7)) * 8),
                      &Ks[nxt][(c * 256 + wid * 64) * 8]);
        }
      }

      // ---- S = Q K^T from Ks[cur] (q pre-scaled by 1/sqrt(D))
      f32x4 s4[2][4];
      #pragma unroll
      for (int f = 0; f < 2; ++f)
        #pragma unroll
        for (int jf = 0; jf < 4; ++jf) s4[f][jf] = (f32x4){0.f, 0.f, 0.f, 0.f};
      #pragma unroll
      for (int jf = 0; jf < 4; ++jf) {
        int krow = jf * 16 + l15;
        #pragma unroll
        for (int kk = 0; kk < 4; ++kk) {
          short8 kf = *(const short8*)((const char*)Ks[cur] + krow * 256 +
                                       ((kk * 64 + g * 16) ^ ((l15 & 7) << 4)));
          s4[0][jf] = mfma16(qf[0][kk], kf, s4[0][jf]);
          s4[1][jf] = mfma16(qf[1][kk], kf, s4[1][jf]);
        }
      }
      // causal mask: last two tiles intersect the diagonal of this q-block
      if (it >= nt - 2) {
        const int kvb = it * KBLK - qt0;   // kv offset relative to q-block base
        #pragma unroll
        for (int f = 0; f < 2; ++f)
          #pragma unroll
          for (int jf = 0; jf < 4; ++jf)
            #pragma unroll
            for (int j = 0; j < 4; ++j)
              if (kvb + jf * 16 + l15 > wid * 32 + f * 16 + 4 * g + j)
                s4[f][jf][j] = -1e30f;
      }
      // ---- online softmax per fragment
      #pragma unroll
      for (int f = 0; f < 2; ++f) {
        float rmax[4], corr[4], rsum[4];
        #pragma unroll
        for (int j = 0; j < 4; ++j)
          rmax[j] = fmaxf(fmaxf(s4[f][0][j], s4[f][1][j]), fmaxf(s4[f][2][j], s4[f][3][j]));
        #pragma unroll
        for (int j = 0; j < 4; ++j) {
          rmax[j] = fmaxf(rmax[j], __shfl_xor(rmax[j], 1, 64));
          rmax[j] = fmaxf(rmax[j], __shfl_xor(rmax[j], 2, 64));
          rmax[j] = fmaxf(rmax[j], __shfl_xor(rmax[j], 4, 64));
          rmax[j] = fmaxf(rmax[j], __shfl_xor(rmax[j], 8, 64));
        }
        #pragma unroll
        for (int j = 0; j < 4; ++j) {
          float mn = fmaxf(mrun[f][j], rmax[j]);
          corr[j] = __expf(mrun[f][j] - mn);
          mrun[f][j] = mn;
        }
        #pragma unroll
        for (int jf = 0; jf < 4; ++jf)
          #pragma unroll
          for (int j = 0; j < 4; ++j)
            s4[f][jf][j] = __expf(s4[f][jf][j] - mrun[f][j]);
        #pragma unroll
        for (int j = 0; j < 4; ++j) {
          rsum[j] = (s4[f][0][j] + s4[f][1][j]) + (s4[f][2][j] + s4[f][3][j]);
          rsum[j] += __shfl_xor(rsum[j], 1, 64);
          rsum[j] += __shfl_xor(rsum[j], 2, 64);
          rsum[j] += __shfl_xor(rsum[j], 4, 64);
          rsum[j] += __shfl_xor(rsum[j], 8, 64);
          lrun[f][j] = lrun[f][j] * corr[j] + rsum[j];
        }
        #pragma unroll
        for (int nf = 0; nf < 8; ++nf)
          #pragma unroll
          for (int j = 0; j < 4; ++j)
            o[f][nf][j] *= corr[j];
      }

      // ---- all waves done reading K from Ks[cur]; reuse it as the P buffer
      __syncthreads();
      // P flat [128 q-rows][64 kv], G4 XOR swizzle: col ^= (row&7)<<3
      {
        u16* Pb = (u16*)Ks[cur];
        #pragma unroll
        for (int f = 0; f < 2; ++f)
          #pragma unroll
          for (int jf = 0; jf < 4; ++jf)
            #pragma unroll
            for (int j = 0; j < 4; ++j) {
              int prow = wid * 32 + f * 16 + 4 * g + j;
              int pcol = (jf * 16 + l15) ^ (((4 * g + j) & 7) << 3);
              Pb[prow * 64 + pcol] = f2bf(s4[f][jf][j]);
            }
      }
      asm volatile("s_waitcnt lgkmcnt(0)" ::: "memory");
      __builtin_amdgcn_sched_barrier(0);
      short8 pf[2][2];
      #pragma unroll
      for (int f = 0; f < 2; ++f)
        #pragma unroll
        for (int kk = 0; kk < 2; ++kk)
          pf[f][kk] = *(const short8*)&((const u16*)Ks[cur])[
              (wid * 32 + f * 16 + l15) * 64 + ((kk * 32 + g * 8) ^ ((l15 & 7) << 3))];

      // ---- O += P V from Vt[cur] (vf read shared across both fragments)
      #pragma unroll
      for (int nf = 0; nf < 8; ++nf) {
        #pragma unroll
        for (int kk = 0; kk < 2; ++kk) {
          short8 vf = *(const short8*)&Vt[cur][(nf * 16 + l15) * PADV + kk * 32 + g * 8];
          o[0][nf] = mfma16(pf[0][kk], vf, o[0][nf]);
          o[1][nf] = mfma16(pf[1][kk], vf, o[1][nf]);
        }
      }

      // ---- late V stage: load+transpose-write just before the drain
      // (short register liveness; latency hidden by the co-resident block)
      if (havenext) {
        const int kvn = (it + 1) * KBLK;
        const u16* vg = qkv + (rb + kvn + vk0) * LD3 + 2 * CC + h * DH + vd0;
        short8 r0 = *(const short8*)vg;
        short8 r1 = *(const short8*)(vg + LD3);
        short8 r2 = *(const short8*)(vg + 2 * LD3);
        short8 r3 = *(const short8*)(vg + 3 * LD3);
        #pragma unroll
        for (int j = 0; j < 8; ++j) {
          ushort4 w;
          w.x = (u16)r0[j]; w.y = (u16)r1[j]; w.z = (u16)r2[j]; w.w = (u16)r3[j];
          *(ushort4*)&Vt[nxt][(vd0 + j) * PADV + vk0] = w;
        }
      }
      asm volatile("s_waitcnt vmcnt(0)" ::: "memory");
      __syncthreads();
    }

    // ---- write back this q-tile
    #pragma unroll
    for (int f = 0; f < 2; ++f) {
      float inv[4];
      #pragma unroll
      for (int j = 0; j < 4; ++j) inv[j] = 1.0f / lrun[f][j];
      #pragma unroll
      for (int nf = 0; nf < 8; ++nf)
        #pragma unroll
        for (int j = 0; j < 4; ++j)
          y[(rb + qt0 + wid * 32 + f * 16 + 4 * g + j) * CC + h * DH + nf * 16 + l15] =
              f2bf(o[f][nf][j] * inv[j]);
    }
  }
}

// ------------------------------------------------------------------ launch
// Workspace layout: non-aliased, 193 MB total.
extern "C" void kernel_launch(void* const* d_in, const int* in_sizes, int n_in,
                              void* d_out, int out_size, void* d_ws, size_t ws_size,
                              hipStream_t stream) {
  const float* x = (const float*)d_in[0];
  const float* Wqkv = (const float*)d_in[1];
  const float* Wproj = (const float*)d_in[2];
  char* ws = (char*)d_ws;
  u16* xb     = (u16*)(ws);                      // 32 MB
  u16* wqkvT  = (u16*)(ws + 33554432);           // 24 MB
  u16* wprojT = (u16*)(ws + 58720256);           // 8 MB
  u16* qkv    = (u16*)(ws + 67108864);           // 96 MB
  u16* y      = (u16*)(ws + 167772160);          // 32 MB
  float2* tab = (float2*)(ws + 201326592);       // 1 MB

  convert_x_kernel<<<4096, 256, 0, stream>>>(x, xb);
  transpose_bf16_kernel<<<dim3(192, 64), dim3(32, 8), 0, stream>>>(Wqkv, wqkvT, CC, N3);
  transpose_bf16_kernel<<<dim3(64, 64), dim3(32, 8), 0, stream>>>(Wproj, wprojT, CC, CC);
  rope_table_kernel<<<512, 256, 0, stream>>>(tab);
  gemm_bt_128<<<dim3(48, 64), 256, 0, stream>>>(xb, wqkvT, (void*)qkv, CC, LD3, 1);
  rope_apply_kernel<<<65536, 256, 0, stream>>>(qkv, tab);
  attn_kernel<<<dim3(8, 64), 256, 0, stream>>>(qkv, y);
  gemm_bt_128<<<dim3(16, 64), 256, 0, stream>>>(y, wprojT, d_out, CC, CC, 0);
}

// Round 8
// 529.720 us; speedup vs baseline: 1.6690x; 1.1979x over previous
//
#include <hip/hip_runtime.h>

// Problem constants
#define BB 4
#define TT 2048
#define CC 2048
#define NHEAD 16
#define DH 128
#define MM (BB * TT)          // 8192 rows
#define N3 (3 * CC)           // 6144
#define LD3 6144

typedef unsigned short u16;
typedef __attribute__((ext_vector_type(8))) short short8;
typedef __attribute__((ext_vector_type(4))) float f32x4;

__device__ __forceinline__ u16 f2bf(float f) {
  unsigned u = __float_as_uint(f);
  u += 0x7fffu + ((u >> 16) & 1u);      // RNE
  return (u16)(u >> 16);
}
__device__ __forceinline__ float bf2f(u16 h) {
  return __uint_as_float(((unsigned)h) << 16);
}

__device__ __forceinline__ void gload_lds16(const void* g, void* l) {
  __builtin_amdgcn_global_load_lds((const __attribute__((address_space(1))) void*)g,
                                   (__attribute__((address_space(3))) void*)l, 16, 0, 0);
}

__device__ __forceinline__ f32x4 mfma16(short8 a, short8 b, f32x4 c) {
  return __builtin_amdgcn_mfma_f32_16x16x32_bf16(a, b, c, 0, 0, 0);
}

// ---------------------------------------------------------------- convert x
__global__ void convert_x_kernel(const float* __restrict__ x, u16* __restrict__ xb) {
  const int total = (MM * CC) / 4;
  const float4* xv = (const float4*)x;
  ushort4* ov = (ushort4*)xb;
  for (int i = blockIdx.x * blockDim.x + threadIdx.x; i < total; i += gridDim.x * blockDim.x) {
    float4 v = xv[i];
    ushort4 o;
    o.x = f2bf(v.x); o.y = f2bf(v.y); o.z = f2bf(v.z); o.w = f2bf(v.w);
    ov[i] = o;
  }
}

// ------------------------------------------- transpose + convert W -> W^T bf16
__global__ void transpose_bf16_kernel(const float* __restrict__ W, u16* __restrict__ Wt,
                                      int rows, int cols) {
  __shared__ float tile[32][33];
  const int n0 = blockIdx.x * 32, k0 = blockIdx.y * 32;
  const int tx = threadIdx.x, ty = threadIdx.y;   // (32, 8)
  #pragma unroll
  for (int i = 0; i < 4; ++i)
    tile[ty + 8 * i][tx] = W[(size_t)(k0 + ty + 8 * i) * cols + n0 + tx];
  __syncthreads();
  #pragma unroll
  for (int i = 0; i < 4; ++i)
    Wt[(size_t)(n0 + ty + 8 * i) * rows + k0 + tx] = f2bf(tile[tx][ty + 8 * i]);
}

// ---------------------------------------------------------------- rope table
__global__ void rope_table_kernel(float2* __restrict__ tab) {
  int idx = blockIdx.x * 256 + threadIdx.x;     // T*64 entries
  int t = idx >> 6, f = idx & 63;
  float freq = expf(-0.14391156831f * (float)f);   // 10000^(-f/64)
  float ang = (float)t * freq;
  float s, c;
  sincosf(ang, &s, &c);
  tab[idx] = make_float2(c, s);
}

// ------------------------------------------------------- rope apply (q and k)
__global__ void rope_apply_kernel(u16* __restrict__ qkv, const float2* __restrict__ tab) {
  int idx = blockIdx.x * 256 + threadIdx.x;   // 2^24 = 2 * M * 16 * 64
  int f = idx & 63;
  int h = (idx >> 6) & 15;
  int m = (idx >> 10) & 8191;
  int which = idx >> 23;                      // 0 = q, 1 = k
  int t = m & (TT - 1);
  u16* p = qkv + (size_t)m * LD3 + which * CC + h * DH + f;
  float2 cs = tab[(t << 6) + f];
  float x1 = bf2f(p[0]), x2 = bf2f(p[64]);
  float o1 = x1 * cs.x - x2 * cs.y;
  float o2 = x2 * cs.x + x1 * cs.y;
  if (which == 0) { o1 *= 0.08838834764831845f; o2 *= 0.08838834764831845f; }
  p[0] = f2bf(o1);
  p[64] = f2bf(o2);
}

// ------------------------------------------------------------------- GEMM
// 256x256 tile, 8 waves (2M x 4N), BK=64, counted-vmcnt pipeline (T3/T4),
// st_16x32 LDS swizzle (T2, rule #21: linear DMA dest + inverse-swizzled
// global source + swizzled ds_read), setprio around MFMA (T5).
//
// Per K-tile schedule (FIFO-verified):
//   STAGE alpha(t+1)={A_lo,B_lo}[4 loads] ; ph1 (m0-3 x n0-1, reads lo)
//   STAGE beta(t+1)={A_hi,B_hi}[4 loads]  ; vmcnt(8)+barrier  [publishes beta(t)]
//   ph2 (m0-3 x n2-3) ; ph3 (m4-7 x n0-1) ; ph4 (m4-7 x n2-3)
//   vmcnt(4)+barrier                       [publishes alpha(t+1)]
// A_lo/hi = per-wave row halves (rows [0,64)u[128,192) / [64,128)u[192,256)),
// B_lo/hi = per-wave n01/n23 strips — so EVERY wave needs beta only in ph2+.
#define TILE_B 32768   // bytes of one [256][64]-bf16 LDS tile

__device__ __forceinline__ int swz9(int x) { return x ^ (((x >> 9) & 1) << 5); }

__device__ __forceinline__ void stage_chunk(const u16* __restrict__ src, int K, int k0,
                                            char* ldsTile, int kind, int wid, int lane) {
  // kind: 0=A_lo 1=A_hi 2=B_lo 3=B_hi ; each chunk = 16KB = 8 waves x 2KB
  #pragma unroll
  for (int c = 0; c < 2; ++c) {
    int x;
    if (kind < 2) {
      x = (kind ? 8192 : 0) + c * 16384 + wid * 1024 + lane * 16;
    } else {
      int wl = wid * 2 + c;
      x = ((kind == 3) ? 4096 : 0) + (wl >> 2) * 8192 + (wl & 3) * 1024 + lane * 16;
    }
    int l = swz9(x);                       // logical byte (involution)
    int r = l >> 7;                        // row 0..255
    int ce = (l >> 1) & 63;                // col element 0..63
    gload_lds16(src + (size_t)r * K + k0 + ce, ldsTile + (x - lane * 16));
  }
}

__global__ __launch_bounds__(512, 2) void gemm_bt_256(const u16* __restrict__ A,
                                                      const u16* __restrict__ Bt,
                                                      void* __restrict__ Cout,
                                                      int K, int ldc, int out_bf16) {
  __shared__ __align__(16) char As[2][TILE_B];
  __shared__ __align__(16) char Bs[2][TILE_B];
  const int tid = threadIdx.x;
  const int wid = tid >> 6, lane = tid & 63;
  const int l15 = lane & 15, g = lane >> 4;
  const int wr = wid >> 2, wc = wid & 3;          // 2M x 4N wave grid
  // T1 XCD swizzle (nwg % 8 == 0 for both call sites)
  const int nwg = gridDim.x * gridDim.y;
  const int orig = blockIdx.y * gridDim.x + blockIdx.x;
  const int swz = (orig & 7) * (nwg >> 3) + (orig >> 3);
  const int bx = swz % gridDim.x, by = swz / gridDim.x;
  const int row0 = by * 256, col0 = bx * 256;

  const u16* Ab = A + (size_t)row0 * K;
  const u16* Bb = Bt + (size_t)col0 * K;

  f32x4 acc[8][4];
  #pragma unroll
  for (int m = 0; m < 8; ++m)
    #pragma unroll
    for (int n = 0; n < 4; ++n) acc[m][n] = (f32x4){0.f, 0.f, 0.f, 0.f};

  // per-thread logical byte bases for fragment reads
  const int abase = (wr * 128 + l15) * 128 + g * 16;   // + m*2048 + ks*64
  const int bbase = (wc * 64 + l15) * 128 + g * 16;    // + n*2048 + ks*64

  // ---- prologue: tile 0 fully staged into buf 0
  stage_chunk(Ab, K, 0, As[0], 0, wid, lane);
  stage_chunk(Bb, K, 0, Bs[0], 2, wid, lane);
  stage_chunk(Ab, K, 0, As[0], 1, wid, lane);
  stage_chunk(Bb, K, 0, Bs[0], 3, wid, lane);
  asm volatile("s_waitcnt vmcnt(0)" ::: "memory");
  __builtin_amdgcn_s_barrier();

  const int nt = K >> 6;
  short8 a[4][2], b[4][2];
  for (int t = 0; t < nt; ++t) {
    const int cur = t & 1, nxt = cur ^ 1;
    const bool hn = (t + 1) < nt;
    const int kn = (t + 1) << 6;
    const char* At = As[cur];
    const char* Btile = Bs[cur];

    if (hn) {                                  // STAGE alpha(t+1)
      stage_chunk(Ab, K, kn, As[nxt], 0, wid, lane);
      stage_chunk(Bb, K, kn, Bs[nxt], 2, wid, lane);
    }
    // ---- ph1: m0-3 x n0-1 (A_lo, B_lo)
    #pragma unroll
    for (int m = 0; m < 4; ++m)
      #pragma unroll
      for (int ks = 0; ks < 2; ++ks)
        a[m][ks] = *(const short8*)(At + swz9(abase + m * 2048 + ks * 64));
    #pragma unroll
    for (int n = 0; n < 2; ++n)
      #pragma unroll
      for (int ks = 0; ks < 2; ++ks)
        b[n][ks] = *(const short8*)(Btile + swz9(bbase + n * 2048 + ks * 64));
    __builtin_amdgcn_s_setprio(1);
    #pragma unroll
    for (int m = 0; m < 4; ++m)
      #pragma unroll
      for (int n = 0; n < 2; ++n)
        #pragma unroll
        for (int ks = 0; ks < 2; ++ks)
          acc[m][n] = mfma16(a[m][ks], b[n][ks], acc[m][n]);
    __builtin_amdgcn_s_setprio(0);

    if (hn) {                                  // STAGE beta(t+1)
      stage_chunk(Ab, K, kn, As[nxt], 1, wid, lane);
      stage_chunk(Bb, K, kn, Bs[nxt], 3, wid, lane);
    }
    // ---- W1: publish beta(t) (leaves alpha(t+1)+beta(t+1) = 8 in flight)
    if (hn) asm volatile("s_waitcnt vmcnt(8)" ::: "memory");
    else    asm volatile("s_waitcnt vmcnt(0)" ::: "memory");
    __builtin_amdgcn_s_barrier();

    // ---- ph2: m0-3 x n2-3 (B_hi)
    #pragma unroll
    for (int n = 2; n < 4; ++n)
      #pragma unroll
      for (int ks = 0; ks < 2; ++ks)
        b[n][ks] = *(const short8*)(Btile + swz9(bbase + n * 2048 + ks * 64));
    __builtin_amdgcn_s_setprio(1);
    #pragma unroll
    for (int m = 0; m < 4; ++m)
      #pragma unroll
      for (int n = 2; n < 4; ++n)
        #pragma unroll
        for (int ks = 0; ks < 2; ++ks)
          acc[m][n] = mfma16(a[m][ks], b[n][ks], acc[m][n]);
    __builtin_amdgcn_s_setprio(0);

    // ---- ph3: m4-7 x n0-1 (A_hi)
    #pragma unroll
    for (int m = 0; m < 4; ++m)
      #pragma unroll
      for (int ks = 0; ks < 2; ++ks)
        a[m][ks] = *(const short8*)(At + swz9(abase + (m + 4) * 2048 + ks * 64));
    __builtin_amdgcn_s_setprio(1);
    #pragma unroll
    for (int m = 0; m < 4; ++m)
      #pragma unroll
      for (int n = 0; n < 2; ++n)
        #pragma unroll
        for (int ks = 0; ks < 2; ++ks)
          acc[m + 4][n] = mfma16(a[m][ks], b[n][ks], acc[m + 4][n]);
    __builtin_amdgcn_s_setprio(0);

    // ---- ph4: m4-7 x n2-3 (all in regs)
    __builtin_amdgcn_s_setprio(1);
    #pragma unroll
    for (int m = 0; m < 4; ++m)
      #pragma unroll
      for (int n = 2; n < 4; ++n)
        #pragma unroll
        for (int ks = 0; ks < 2; ++ks)
          acc[m + 4][n] = mfma16(a[m][ks], b[n][ks], acc[m + 4][n]);
    __builtin_amdgcn_s_setprio(0);

    // ---- W2: publish alpha(t+1) (leaves beta(t+1) = 4 in flight)
    if (hn) {
      asm volatile("s_waitcnt vmcnt(4)" ::: "memory");
      __builtin_amdgcn_s_barrier();
    }
  }

  // ---- epilogue
  if (out_bf16) {
    u16* Cb = (u16*)Cout;
    #pragma unroll
    for (int m = 0; m < 8; ++m)
      #pragma unroll
      for (int n = 0; n < 4; ++n) {
        int row = row0 + wr * 128 + m * 16 + 4 * g;
        int col = col0 + wc * 64 + n * 16 + l15;
        #pragma unroll
        for (int j = 0; j < 4; ++j)
          Cb[(size_t)(row + j) * ldc + col] = f2bf(acc[m][n][j]);
      }
  } else {
    float* Cf = (float*)Cout;
    #pragma unroll
    for (int m = 0; m < 8; ++m)
      #pragma unroll
      for (int n = 0; n < 4; ++n) {
        int row = row0 + wr * 128 + m * 16 + 4 * g;
        int col = col0 + wc * 64 + n * 16 + l15;
        #pragma unroll
        for (int j = 0; j < 4; ++j)
          Cf[(size_t)(row + j) * ldc + col] = acc[m][n][j];
      }
  }
}

// ---------------------------------------------------------------- attention
// QBLK=128, diagonal pairing (uniform 34 iters/block), 512 blocks, 2 blocks/CU.
#define QBLK 128
#define KBLK 64
#define PADV 72

__global__ __launch_bounds__(256, 2) void attn_kernel(const u16* __restrict__ qkv,
                                                      u16* __restrict__ y) {
  __shared__ __align__(16) u16 Ks[2][KBLK * 128];   // K tile (swizzled) / P buffer
  __shared__ __align__(16) u16 Vt[2][DH * PADV];    // V^T [d][kv], padded
  const int tid = threadIdx.x;
  const int wid = tid >> 6, lane = tid & 63;
  const int l15 = lane & 15, g = lane >> 4;
  const int b = blockIdx.y >> 4, h = blockIdx.y & 15;
  const size_t rb = (size_t)b * TT;
  const int vk0 = (tid & 15) * 4, vd0 = (tid >> 4) * 8;   // V-staging assignment

  for (int half = 0; half < 2; ++half) {
    const int qt0 = (half ? (15 - (int)blockIdx.x) : (int)blockIdx.x) * QBLK;

    // ---- Q fragments straight from global (one-time; rows 12KB apart)
    short8 qf[2][4];
    {
      const u16* qbase = qkv + (rb + qt0 + wid * 32 + l15) * LD3 + h * DH;
      #pragma unroll
      for (int f = 0; f < 2; ++f)
        #pragma unroll
        for (int kk = 0; kk < 4; ++kk)
          qf[f][kk] = *(const short8*)(qbase + f * 16 * LD3 + kk * 32 + g * 8);
    }

    // ---- prologue: stage K(tile0) -> Ks[0], V(tile0) -> Vt[0]
    {
      const u16* kbase = qkv + (rb)*LD3 + CC + h * DH;
      #pragma unroll
      for (int c = 0; c < 4; ++c) {
        int chunk = c * 256 + tid;
        int r = chunk >> 4, s = chunk & 15;
        gload_lds16(kbase + (size_t)r * LD3 + (size_t)((s ^ (r & 7)) * 8),
                    &Ks[0][(c * 256 + wid * 64) * 8]);
      }
      const u16* vg = qkv + (rb + vk0) * LD3 + 2 * CC + h * DH + vd0;
      short8 r0 = *(const short8*)vg;
      short8 r1 = *(const short8*)(vg + LD3);
      short8 r2 = *(const short8*)(vg + 2 * LD3);
      short8 r3 = *(const short8*)(vg + 3 * LD3);
      #pragma unroll
      for (int j = 0; j < 8; ++j) {
        ushort4 w;
        w.x = (u16)r0[j]; w.y = (u16)r1[j]; w.z = (u16)r2[j]; w.w = (u16)r3[j];
        *(ushort4*)&Vt[0][(vd0 + j) * PADV + vk0] = w;
      }
    }
    asm volatile("s_waitcnt vmcnt(0)" ::: "memory");
    __syncthreads();

    f32x4 o[2][8];
    float mrun[2][4], lrun[2][4];
    #pragma unroll
    for (int f = 0; f < 2; ++f) {
      #pragma unroll
      for (int nf = 0; nf < 8; ++nf) o[f][nf] = (f32x4){0.f, 0.f, 0.f, 0.f};
      #pragma unroll
      for (int j = 0; j < 4; ++j) { mrun[f][j] = -1e30f; lrun[f][j] = 0.f; }
    }

    const int nt = qt0 / KBLK + 2;         // kv tiles (last two intersect diagonal)
    for (int it = 0; it < nt; ++it) {
      const int cur = it & 1, nxt = cur ^ 1;
      const bool havenext = (it + 1) < nt;
      if (havenext) {
        const int kvn = (it + 1) * KBLK;
        const u16* kbase = qkv + (rb + kvn) * LD3 + CC + h * DH;
        #pragma unroll
        for (int c = 0; c < 4; ++c) {
          int chunk = c * 256 + tid;
          int r = chunk >> 4, s = chunk & 15;
          gload_lds16(kbase + (size_t)r * LD3 + (size_t)((s ^ (r & 7)) * 8),
                      &Ks[nxt][(c * 256 + wid * 64) * 8]);
        }
      }

      // ---- S = Q K^T from Ks[cur] (q pre-scaled by 1/sqrt(D))
      f32x4 s4[2][4];
      #pragma unroll
      for (int f = 0; f < 2; ++f)
        #pragma unroll
        for (int jf = 0; jf < 4; ++jf) s4[f][jf] = (f32x4){0.f, 0.f, 0.f, 0.f};
      #pragma unroll
      for (int jf = 0; jf < 4; ++jf) {
        int krow = jf * 16 + l15;
        #pragma unroll
        for (int kk = 0; kk < 4; ++kk) {
          short8 kf = *(const short8*)((const char*)Ks[cur] + krow * 256 +
                                       ((kk * 64 + g * 16) ^ ((l15 & 7) << 4)));
          s4[0][jf] = mfma16(qf[0][kk], kf, s4[0][jf]);
          s4[1][jf] = mfma16(qf[1][kk], kf, s4[1][jf]);
        }
      }
      // causal mask: last two tiles intersect the diagonal of this q-block
      if (it >= nt - 2) {
        const int kvb = it * KBLK - qt0;   // kv offset relative to q-block base
        #pragma unroll
        for (int f = 0; f < 2; ++f)
          #pragma unroll
          for (int jf = 0; jf < 4; ++jf)
            #pragma unroll
            for (int j = 0; j < 4; ++j)
              if (kvb + jf * 16 + l15 > wid * 32 + f * 16 + 4 * g + j)
                s4[f][jf][j] = -1e30f;
      }
      // ---- online softmax per fragment
      #pragma unroll
      for (int f = 0; f < 2; ++f) {
        float rmax[4], corr[4], rsum[4];
        #pragma unroll
        for (int j = 0; j < 4; ++j)
          rmax[j] = fmaxf(fmaxf(s4[f][0][j], s4[f][1][j]), fmaxf(s4[f][2][j], s4[f][3][j]));
        #pragma unroll
        for (int j = 0; j < 4; ++j) {
          rmax[j] = fmaxf(rmax[j], __shfl_xor(rmax[j], 1, 64));
          rmax[j] = fmaxf(rmax[j], __shfl_xor(rmax[j], 2, 64));
          rmax[j] = fmaxf(rmax[j], __shfl_xor(rmax[j], 4, 64));
          rmax[j] = fmaxf(rmax[j], __shfl_xor(rmax[j], 8, 64));
        }
        #pragma unroll
        for (int j = 0; j < 4; ++j) {
          float mn = fmaxf(mrun[f][j], rmax[j]);
          corr[j] = __expf(mrun[f][j] - mn);
          mrun[f][j] = mn;
        }
        #pragma unroll
        for (int jf = 0; jf < 4; ++jf)
          #pragma unroll
          for (int j = 0; j < 4; ++j)
            s4[f][jf][j] = __expf(s4[f][jf][j] - mrun[f][j]);
        #pragma unroll
        for (int j = 0; j < 4; ++j) {
          rsum[j] = (s4[f][0][j] + s4[f][1][j]) + (s4[f][2][j] + s4[f][3][j]);
          rsum[j] += __shfl_xor(rsum[j], 1, 64);
          rsum[j] += __shfl_xor(rsum[j], 2, 64);
          rsum[j] += __shfl_xor(rsum[j], 4, 64);
          rsum[j] += __shfl_xor(rsum[j], 8, 64);
          lrun[f][j] = lrun[f][j] * corr[j] + rsum[j];
        }
        #pragma unroll
        for (int nf = 0; nf < 8; ++nf)
          #pragma unroll
          for (int j = 0; j < 4; ++j)
            o[f][nf][j] *= corr[j];
      }

      // ---- all waves done reading K from Ks[cur]; reuse it as the P buffer
      __syncthreads();
      // P flat [128 q-rows][64 kv], G4 XOR swizzle: col ^= (row&7)<<3
      {
        u16* Pb = (u16*)Ks[cur];
        #pragma unroll
        for (int f = 0; f < 2; ++f)
          #pragma unroll
          for (int jf = 0; jf < 4; ++jf)
            #pragma unroll
            for (int j = 0; j < 4; ++j) {
              int prow = wid * 32 + f * 16 + 4 * g + j;
              int pcol = (jf * 16 + l15) ^ (((4 * g + j) & 7) << 3);
              Pb[prow * 64 + pcol] = f2bf(s4[f][jf][j]);
            }
      }
      asm volatile("s_waitcnt lgkmcnt(0)" ::: "memory");
      __builtin_amdgcn_sched_barrier(0);
      short8 pf[2][2];
      #pragma unroll
      for (int f = 0; f < 2; ++f)
        #pragma unroll
        for (int kk = 0; kk < 2; ++kk)
          pf[f][kk] = *(const short8*)&((const u16*)Ks[cur])[
              (wid * 32 + f * 16 + l15) * 64 + ((kk * 32 + g * 8) ^ ((l15 & 7) << 3))];

      // ---- O += P V from Vt[cur] (vf read shared across both fragments)
      #pragma unroll
      for (int nf = 0; nf < 8; ++nf) {
        #pragma unroll
        for (int kk = 0; kk < 2; ++kk) {
          short8 vf = *(const short8*)&Vt[cur][(nf * 16 + l15) * PADV + kk * 32 + g * 8];
          o[0][nf] = mfma16(pf[0][kk], vf, o[0][nf]);
          o[1][nf] = mfma16(pf[1][kk], vf, o[1][nf]);
        }
      }

      // ---- late V stage: load+transpose-write just before the drain
      if (havenext) {
        const int kvn = (it + 1) * KBLK;
        const u16* vg = qkv + (rb + kvn + vk0) * LD3 + 2 * CC + h * DH + vd0;
        short8 r0 = *(const short8*)vg;
        short8 r1 = *(const short8*)(vg + LD3);
        short8 r2 = *(const short8*)(vg + 2 * LD3);
        short8 r3 = *(const short8*)(vg + 3 * LD3);
        #pragma unroll
        for (int j = 0; j < 8; ++j) {
          ushort4 w;
          w.x = (u16)r0[j]; w.y = (u16)r1[j]; w.z = (u16)r2[j]; w.w = (u16)r3[j];
          *(ushort4*)&Vt[nxt][(vd0 + j) * PADV + vk0] = w;
        }
      }
      asm volatile("s_waitcnt vmcnt(0)" ::: "memory");
      __syncthreads();
    }

    // ---- write back this q-tile
    #pragma unroll
    for (int f = 0; f < 2; ++f) {
      float inv[4];
      #pragma unroll
      for (int j = 0; j < 4; ++j) inv[j] = 1.0f / lrun[f][j];
      #pragma unroll
      for (int nf = 0; nf < 8; ++nf)
        #pragma unroll
        for (int j = 0; j < 4; ++j)
          y[(rb + qt0 + wid * 32 + f * 16 + 4 * g + j) * CC + h * DH + nf * 16 + l15] =
              f2bf(o[f][nf][j] * inv[j]);
    }
  }
}

// ------------------------------------------------------------------ launch
// Workspace layout: non-aliased, 193 MB total.
extern "C" void kernel_launch(void* const* d_in, const int* in_sizes, int n_in,
                              void* d_out, int out_size, void* d_ws, size_t ws_size,
                              hipStream_t stream) {
  const float* x = (const float*)d_in[0];
  const float* Wqkv = (const float*)d_in[1];
  const float* Wproj = (const float*)d_in[2];
  char* ws = (char*)d_ws;
  u16* xb     = (u16*)(ws);                      // 32 MB
  u16* wqkvT  = (u16*)(ws + 33554432);           // 24 MB
  u16* wprojT = (u16*)(ws + 58720256);           // 8 MB
  u16* qkv    = (u16*)(ws + 67108864);           // 96 MB
  u16* y      = (u16*)(ws + 167772160);          // 32 MB
  float2* tab = (float2*)(ws + 201326592);       // 1 MB

  convert_x_kernel<<<4096, 256, 0, stream>>>(x, xb);
  transpose_bf16_kernel<<<dim3(192, 64), dim3(32, 8), 0, stream>>>(Wqkv, wqkvT, CC, N3);
  transpose_bf16_kernel<<<dim3(64, 64), dim3(32, 8), 0, stream>>>(Wproj, wprojT, CC, CC);
  rope_table_kernel<<<512, 256, 0, stream>>>(tab);
  gemm_bt_256<<<dim3(24, 32), 512, 0, stream>>>(xb, wqkvT, (void*)qkv, CC, LD3, 1);
  rope_apply_kernel<<<65536, 256, 0, stream>>>(qkv, tab);
  attn_kernel<<<dim3(8, 64), 256, 0, stream>>>(qkv, y);
  gemm_bt_256<<<dim3(8, 32), 512, 0, stream>>>(y, wprojT, d_out, CC, CC, 0);
}

// Round 9
// 517.348 us; speedup vs baseline: 1.7089x; 1.0239x over previous
//
#include <hip/hip_runtime.h>

// Problem constants
#define BB 4
#define TT 2048
#define CC 2048
#define NHEAD 16
#define DH 128
#define MM (BB * TT)          // 8192 rows
#define N3 (3 * CC)           // 6144
#define LD3 6144

typedef unsigned short u16;
typedef __attribute__((ext_vector_type(8))) short short8;
typedef __attribute__((ext_vector_type(4))) float f32x4;

__device__ __forceinline__ u16 f2bf(float f) {
  unsigned u = __float_as_uint(f);
  u += 0x7fffu + ((u >> 16) & 1u);      // RNE
  return (u16)(u >> 16);
}
__device__ __forceinline__ float bf2f(u16 h) {
  return __uint_as_float(((unsigned)h) << 16);
}

__device__ __forceinline__ void gload_lds16(const void* g, void* l) {
  __builtin_amdgcn_global_load_lds((const __attribute__((address_space(1))) void*)g,
                                   (__attribute__((address_space(3))) void*)l, 16, 0, 0);
}

__device__ __forceinline__ f32x4 mfma16(short8 a, short8 b, f32x4 c) {
  return __builtin_amdgcn_mfma_f32_16x16x32_bf16(a, b, c, 0, 0, 0);
}

// ---------------------------------------------------------------- convert x
__global__ void convert_x_kernel(const float* __restrict__ x, u16* __restrict__ xb) {
  const int total = (MM * CC) / 4;
  const float4* xv = (const float4*)x;
  ushort4* ov = (ushort4*)xb;
  for (int i = blockIdx.x * blockDim.x + threadIdx.x; i < total; i += gridDim.x * blockDim.x) {
    float4 v = xv[i];
    ushort4 o;
    o.x = f2bf(v.x); o.y = f2bf(v.y); o.z = f2bf(v.z); o.w = f2bf(v.w);
    ov[i] = o;
  }
}

// ------------------------------------------- transpose + convert W -> W^T bf16
__global__ void transpose_bf16_kernel(const float* __restrict__ W, u16* __restrict__ Wt,
                                      int rows, int cols) {
  __shared__ float tile[32][33];
  const int n0 = blockIdx.x * 32, k0 = blockIdx.y * 32;
  const int tx = threadIdx.x, ty = threadIdx.y;   // (32, 8)
  #pragma unroll
  for (int i = 0; i < 4; ++i)
    tile[ty + 8 * i][tx] = W[(size_t)(k0 + ty + 8 * i) * cols + n0 + tx];
  __syncthreads();
  #pragma unroll
  for (int i = 0; i < 4; ++i)
    Wt[(size_t)(n0 + ty + 8 * i) * rows + k0 + tx] = f2bf(tile[tx][ty + 8 * i]);
}

// ---------------------------------------------------------------- rope table
__global__ void rope_table_kernel(float2* __restrict__ tab) {
  int idx = blockIdx.x * 256 + threadIdx.x;     // T*64 entries
  int t = idx >> 6, f = idx & 63;
  float freq = expf(-0.14391156831f * (float)f);   // 10000^(-f/64)
  float ang = (float)t * freq;
  float s, c;
  sincosf(ang, &s, &c);
  tab[idx] = make_float2(c, s);
}

// ------------------------------------------------------- rope apply (q and k)
// Vectorized: each thread rotates 8 contiguous freq pairs (short8 loads).
__global__ void rope_apply_kernel(u16* __restrict__ qkv, const float2* __restrict__ tab) {
  int idx = blockIdx.x * 256 + threadIdx.x;   // 2^21 = 2 * M * 16 * 8
  int f8 = idx & 7;
  int h = (idx >> 3) & 15;
  int m = (idx >> 7) & 8191;
  int which = idx >> 20;                      // 0 = q, 1 = k
  int t = m & (TT - 1);
  u16* p = qkv + (size_t)m * LD3 + which * CC + h * DH + f8 * 8;
  short8 v1 = *(const short8*)p;
  short8 v2 = *(const short8*)(p + 64);
  const float2* cs = &tab[(t << 6) + f8 * 8];
  const float scale = which ? 1.0f : 0.08838834764831845f;
  short8 o1, o2;
  #pragma unroll
  for (int j = 0; j < 8; ++j) {
    float2 c = cs[j];
    float x1 = bf2f((u16)v1[j]), x2 = bf2f((u16)v2[j]);
    o1[j] = (short)f2bf((x1 * c.x - x2 * c.y) * scale);
    o2[j] = (short)f2bf((x2 * c.x + x1 * c.y) * scale);
  }
  *(short8*)p = o1;
  *(short8*)(p + 64) = o2;
}

// ------------------------------------------------------------------- GEMM
// 256x256 tile, 8 waves (2M x 4N), BK=64, counted-vmcnt pipeline (T3/T4),
// LDS swizzle: XOR low-3 row bits into byte bits 4-6 (rule #21 both sides:
// linear DMA dest + inverse-swizzled global source + swizzled ds_read).
// R8 post-mortem: swz9 (bit9->bit5) only 2-way-split consecutive lanes ->
// ~4-way cycle-group conflicts (1.89e7). swz47 spreads 8 consecutive rows
// over all 8 16B slots of the 128B row -> free 2-way.
#define TILE_B 32768   // bytes of one [256][64]-bf16 LDS tile

__device__ __forceinline__ int swz47(int x) { return x ^ (((x >> 7) & 7) << 4); }

__device__ __forceinline__ void stage_chunk(const u16* __restrict__ src, int K, int k0,
                                            char* ldsTile, int kind, int wid, int lane) {
  // kind: 0=A_lo 1=A_hi 2=B_lo 3=B_hi ; each chunk = 16KB = 8 waves x 2KB
  #pragma unroll
  for (int c = 0; c < 2; ++c) {
    int x;
    if (kind < 2) {
      x = (kind ? 8192 : 0) + c * 16384 + wid * 1024 + lane * 16;
    } else {
      int wl = wid * 2 + c;
      x = ((kind == 3) ? 4096 : 0) + (wl >> 2) * 8192 + (wl & 3) * 1024 + lane * 16;
    }
    int l = swz47(x);                      // logical byte (involution, row-preserving)
    int r = l >> 7;                        // row 0..255
    int ce = (l >> 1) & 63;                // col element 0..63 (16B-aligned)
    gload_lds16(src + (size_t)r * K + k0 + ce, ldsTile + (x - lane * 16));
  }
}

__global__ __launch_bounds__(512, 2) void gemm_bt_256(const u16* __restrict__ A,
                                                      const u16* __restrict__ Bt,
                                                      void* __restrict__ Cout,
                                                      int K, int ldc, int out_bf16) {
  __shared__ __align__(16) char As[2][TILE_B];
  __shared__ __align__(16) char Bs[2][TILE_B];
  const int tid = threadIdx.x;
  const int wid = tid >> 6, lane = tid & 63;
  const int l15 = lane & 15, g = lane >> 4;
  const int wr = wid >> 2, wc = wid & 3;          // 2M x 4N wave grid
  // T1 XCD swizzle (nwg % 8 == 0 for both call sites)
  const int nwg = gridDim.x * gridDim.y;
  const int orig = blockIdx.y * gridDim.x + blockIdx.x;
  const int swz = (orig & 7) * (nwg >> 3) + (orig >> 3);
  const int bx = swz % gridDim.x, by = swz / gridDim.x;
  const int row0 = by * 256, col0 = bx * 256;

  const u16* Ab = A + (size_t)row0 * K;
  const u16* Bb = Bt + (size_t)col0 * K;

  f32x4 acc[8][4];
  #pragma unroll
  for (int m = 0; m < 8; ++m)
    #pragma unroll
    for (int n = 0; n < 4; ++n) acc[m][n] = (f32x4){0.f, 0.f, 0.f, 0.f};

  // per-thread logical byte bases for fragment reads
  const int abase = (wr * 128 + l15) * 128 + g * 16;   // + m*2048 + ks*64
  const int bbase = (wc * 64 + l15) * 128 + g * 16;    // + n*2048 + ks*64

  // ---- prologue: tile 0 fully staged into buf 0
  stage_chunk(Ab, K, 0, As[0], 0, wid, lane);
  stage_chunk(Bb, K, 0, Bs[0], 2, wid, lane);
  stage_chunk(Ab, K, 0, As[0], 1, wid, lane);
  stage_chunk(Bb, K, 0, Bs[0], 3, wid, lane);
  asm volatile("s_waitcnt vmcnt(0)" ::: "memory");
  __builtin_amdgcn_s_barrier();

  const int nt = K >> 6;
  short8 a[4][2], b[4][2];
  for (int t = 0; t < nt; ++t) {
    const int cur = t & 1, nxt = cur ^ 1;
    const bool hn = (t + 1) < nt;
    const int kn = (t + 1) << 6;
    const char* At = As[cur];
    const char* Btile = Bs[cur];

    if (hn) {                                  // STAGE alpha(t+1)
      stage_chunk(Ab, K, kn, As[nxt], 0, wid, lane);
      stage_chunk(Bb, K, kn, Bs[nxt], 2, wid, lane);
    }
    // ---- ph1: m0-3 x n0-1 (A_lo, B_lo)
    #pragma unroll
    for (int m = 0; m < 4; ++m)
      #pragma unroll
      for (int ks = 0; ks < 2; ++ks)
        a[m][ks] = *(const short8*)(At + swz47(abase + m * 2048 + ks * 64));
    #pragma unroll
    for (int n = 0; n < 2; ++n)
      #pragma unroll
      for (int ks = 0; ks < 2; ++ks)
        b[n][ks] = *(const short8*)(Btile + swz47(bbase + n * 2048 + ks * 64));
    __builtin_amdgcn_s_setprio(1);
    #pragma unroll
    for (int m = 0; m < 4; ++m)
      #pragma unroll
      for (int n = 0; n < 2; ++n)
        #pragma unroll
        for (int ks = 0; ks < 2; ++ks)
          acc[m][n] = mfma16(a[m][ks], b[n][ks], acc[m][n]);
    __builtin_amdgcn_s_setprio(0);

    if (hn) {                                  // STAGE beta(t+1)
      stage_chunk(Ab, K, kn, As[nxt], 1, wid, lane);
      stage_chunk(Bb, K, kn, Bs[nxt], 3, wid, lane);
    }
    // ---- W1: publish beta(t) (leaves alpha(t+1)+beta(t+1) = 8 in flight)
    if (hn) asm volatile("s_waitcnt vmcnt(8)" ::: "memory");
    else    asm volatile("s_waitcnt vmcnt(0)" ::: "memory");
    __builtin_amdgcn_s_barrier();

    // ---- ph2: m0-3 x n2-3 (B_hi)
    #pragma unroll
    for (int n = 2; n < 4; ++n)
      #pragma unroll
      for (int ks = 0; ks < 2; ++ks)
        b[n][ks] = *(const short8*)(Btile + swz47(bbase + n * 2048 + ks * 64));
    __builtin_amdgcn_s_setprio(1);
    #pragma unroll
    for (int m = 0; m < 4; ++m)
      #pragma unroll
      for (int n = 2; n < 4; ++n)
        #pragma unroll
        for (int ks = 0; ks < 2; ++ks)
          acc[m][n] = mfma16(a[m][ks], b[n][ks], acc[m][n]);
    __builtin_amdgcn_s_setprio(0);

    // ---- ph3: m4-7 x n0-1 (A_hi)
    #pragma unroll
    for (int m = 0; m < 4; ++m)
      #pragma unroll
      for (int ks = 0; ks < 2; ++ks)
        a[m][ks] = *(const short8*)(At + swz47(abase + (m + 4) * 2048 + ks * 64));
    __builtin_amdgcn_s_setprio(1);
    #pragma unroll
    for (int m = 0; m < 4; ++m)
      #pragma unroll
      for (int n = 0; n < 2; ++n)
        #pragma unroll
        for (int ks = 0; ks < 2; ++ks)
          acc[m + 4][n] = mfma16(a[m][ks], b[n][ks], acc[m + 4][n]);
    __builtin_amdgcn_s_setprio(0);

    // ---- ph4: m4-7 x n2-3 (all in regs)
    __builtin_amdgcn_s_setprio(1);
    #pragma unroll
    for (int m = 0; m < 4; ++m)
      #pragma unroll
      for (int n = 2; n < 4; ++n)
        #pragma unroll
        for (int ks = 0; ks < 2; ++ks)
          acc[m + 4][n] = mfma16(a[m][ks], b[n][ks], acc[m + 4][n]);
    __builtin_amdgcn_s_setprio(0);

    // ---- W2: publish alpha(t+1) (leaves beta(t+1) = 4 in flight)
    if (hn) {
      asm volatile("s_waitcnt vmcnt(4)" ::: "memory");
      __builtin_amdgcn_s_barrier();
    }
  }

  // ---- epilogue
  if (out_bf16) {
    u16* Cb = (u16*)Cout;
    #pragma unroll
    for (int m = 0; m < 8; ++m)
      #pragma unroll
      for (int n = 0; n < 4; ++n) {
        int row = row0 + wr * 128 + m * 16 + 4 * g;
        int col = col0 + wc * 64 + n * 16 + l15;
        #pragma unroll
        for (int j = 0; j < 4; ++j)
          Cb[(size_t)(row + j) * ldc + col] = f2bf(acc[m][n][j]);
      }
  } else {
    float* Cf = (float*)Cout;
    #pragma unroll
    for (int m = 0; m < 8; ++m)
      #pragma unroll
      for (int n = 0; n < 4; ++n) {
        int row = row0 + wr * 128 + m * 16 + 4 * g;
        int col = col0 + wc * 64 + n * 16 + l15;
        #pragma unroll
        for (int j = 0; j < 4; ++j)
          Cf[(size_t)(row + j) * ldc + col] = acc[m][n][j];
      }
  }
}

// ---------------------------------------------------------------- attention
// QBLK=128, diagonal pairing (uniform 34 iters/block), 512 blocks, 2 blocks/CU.
#define QBLK 128
#define KBLK 64
#define PADV 72

__global__ __launch_bounds__(256, 2) void attn_kernel(const u16* __restrict__ qkv,
                                                      u16* __restrict__ y) {
  __shared__ __align__(16) u16 Ks[2][KBLK * 128];   // K tile (swizzled) / P buffer
  __shared__ __align__(16) u16 Vt[2][DH * PADV];    // V^T [d][kv], padded
  const int tid = threadIdx.x;
  const int wid = tid >> 6, lane = tid & 63;
  const int l15 = lane & 15, g = lane >> 4;
  const int b = blockIdx.y >> 4, h = blockIdx.y & 15;
  const size_t rb = (size_t)b * TT;
  const int vk0 = (tid & 15) * 4, vd0 = (tid >> 4) * 8;   // V-staging assignment

  for (int half = 0; half < 2; ++half) {
    const int qt0 = (half ? (15 - (int)blockIdx.x) : (int)blockIdx.x) * QBLK;

    // ---- Q fragments straight from global (one-time; rows 12KB apart)
    short8 qf[2][4];
    {
      const u16* qbase = qkv + (rb + qt0 + wid * 32 + l15) * LD3 + h * DH;
      #pragma unroll
      for (int f = 0; f < 2; ++f)
        #pragma unroll
        for (int kk = 0; kk < 4; ++kk)
          qf[f][kk] = *(const short8*)(qbase + f * 16 * LD3 + kk * 32 + g * 8);
    }

    // ---- prologue: stage K(tile0) -> Ks[0], V(tile0) -> Vt[0]
    {
      const u16* kbase = qkv + (rb)*LD3 + CC + h * DH;
      #pragma unroll
      for (int c = 0; c < 4; ++c) {
        int chunk = c * 256 + tid;
        int r = chunk >> 4, s = chunk & 15;
        gload_lds16(kbase + (size_t)r * LD3 + (size_t)((s ^ (r & 7)) * 8),
                    &Ks[0][(c * 256 + wid * 64) * 8]);
      }
      const u16* vg = qkv + (rb + vk0) * LD3 + 2 * CC + h * DH + vd0;
      short8 r0 = *(const short8*)vg;
      short8 r1 = *(const short8*)(vg + LD3);
      short8 r2 = *(const short8*)(vg + 2 * LD3);
      short8 r3 = *(const short8*)(vg + 3 * LD3);
      #pragma unroll
      for (int j = 0; j < 8; ++j) {
        ushort4 w;
        w.x = (u16)r0[j]; w.y = (u16)r1[j]; w.z = (u16)r2[j]; w.w = (u16)r3[j];
        *(ushort4*)&Vt[0][(vd0 + j) * PADV + vk0] = w;
      }
    }
    asm volatile("s_waitcnt vmcnt(0)" ::: "memory");
    __syncthreads();

    f32x4 o[2][8];
    float mrun[2][4], lrun[2][4];
    #pragma unroll
    for (int f = 0; f < 2; ++f) {
      #pragma unroll
      for (int nf = 0; nf < 8; ++nf) o[f][nf] = (f32x4){0.f, 0.f, 0.f, 0.f};
      #pragma unroll
      for (int j = 0; j < 4; ++j) { mrun[f][j] = -1e30f; lrun[f][j] = 0.f; }
    }

    const int nt = qt0 / KBLK + 2;         // kv tiles (last two intersect diagonal)
    for (int it = 0; it < nt; ++it) {
      const int cur = it & 1, nxt = cur ^ 1;
      const bool havenext = (it + 1) < nt;
      if (havenext) {
        const int kvn = (it + 1) * KBLK;
        const u16* kbase = qkv + (rb + kvn) * LD3 + CC + h * DH;
        #pragma unroll
        for (int c = 0; c < 4; ++c) {
          int chunk = c * 256 + tid;
          int r = chunk >> 4, s = chunk & 15;
          gload_lds16(kbase + (size_t)r * LD3 + (size_t)((s ^ (r & 7)) * 8),
                      &Ks[nxt][(c * 256 + wid * 64) * 8]);
        }
      }

      // ---- S = Q K^T from Ks[cur] (q pre-scaled by 1/sqrt(D))
      f32x4 s4[2][4];
      #pragma unroll
      for (int f = 0; f < 2; ++f)
        #pragma unroll
        for (int jf = 0; jf < 4; ++jf) s4[f][jf] = (f32x4){0.f, 0.f, 0.f, 0.f};
      #pragma unroll
      for (int jf = 0; jf < 4; ++jf) {
        int krow = jf * 16 + l15;
        #pragma unroll
        for (int kk = 0; kk < 4; ++kk) {
          short8 kf = *(const short8*)((const char*)Ks[cur] + krow * 256 +
                                       ((kk * 64 + g * 16) ^ ((l15 & 7) << 4)));
          s4[0][jf] = mfma16(qf[0][kk], kf, s4[0][jf]);
          s4[1][jf] = mfma16(qf[1][kk], kf, s4[1][jf]);
        }
      }
      // causal mask: last two tiles intersect the diagonal of this q-block
      if (it >= nt - 2) {
        const int kvb = it * KBLK - qt0;   // kv offset relative to q-block base
        #pragma unroll
        for (int f = 0; f < 2; ++f)
          #pragma unroll
          for (int jf = 0; jf < 4; ++jf)
            #pragma unroll
            for (int j = 0; j < 4; ++j)
              if (kvb + jf * 16 + l15 > wid * 32 + f * 16 + 4 * g + j)
                s4[f][jf][j] = -1e30f;
      }
      // ---- online softmax per fragment
      #pragma unroll
      for (int f = 0; f < 2; ++f) {
        float rmax[4], corr[4], rsum[4];
        #pragma unroll
        for (int j = 0; j < 4; ++j)
          rmax[j] = fmaxf(fmaxf(s4[f][0][j], s4[f][1][j]), fmaxf(s4[f][2][j], s4[f][3][j]));
        #pragma unroll
        for (int j = 0; j < 4; ++j) {
          rmax[j] = fmaxf(rmax[j], __shfl_xor(rmax[j], 1, 64));
          rmax[j] = fmaxf(rmax[j], __shfl_xor(rmax[j], 2, 64));
          rmax[j] = fmaxf(rmax[j], __shfl_xor(rmax[j], 4, 64));
          rmax[j] = fmaxf(rmax[j], __shfl_xor(rmax[j], 8, 64));
        }
        #pragma unroll
        for (int j = 0; j < 4; ++j) {
          float mn = fmaxf(mrun[f][j], rmax[j]);
          corr[j] = __expf(mrun[f][j] - mn);
          mrun[f][j] = mn;
        }
        #pragma unroll
        for (int jf = 0; jf < 4; ++jf)
          #pragma unroll
          for (int j = 0; j < 4; ++j)
            s4[f][jf][j] = __expf(s4[f][jf][j] - mrun[f][j]);
        #pragma unroll
        for (int j = 0; j < 4; ++j) {
          rsum[j] = (s4[f][0][j] + s4[f][1][j]) + (s4[f][2][j] + s4[f][3][j]);
          rsum[j] += __shfl_xor(rsum[j], 1, 64);
          rsum[j] += __shfl_xor(rsum[j], 2, 64);
          rsum[j] += __shfl_xor(rsum[j], 4, 64);
          rsum[j] += __shfl_xor(rsum[j], 8, 64);
          lrun[f][j] = lrun[f][j] * corr[j] + rsum[j];
        }
        #pragma unroll
        for (int nf = 0; nf < 8; ++nf)
          #pragma unroll
          for (int j = 0; j < 4; ++j)
            o[f][nf][j] *= corr[j];
      }

      // ---- all waves done reading K from Ks[cur]; reuse it as the P buffer
      __syncthreads();
      // P flat [128 q-rows][64 kv], G4 XOR swizzle: col ^= (row&7)<<3
      {
        u16* Pb = (u16*)Ks[cur];
        #pragma unroll
        for (int f = 0; f < 2; ++f)
          #pragma unroll
          for (int jf = 0; jf < 4; ++jf)
            #pragma unroll
            for (int j = 0; j < 4; ++j) {
              int prow = wid * 32 + f * 16 + 4 * g + j;
              int pcol = (jf * 16 + l15) ^ (((4 * g + j) & 7) << 3);
              Pb[prow * 64 + pcol] = f2bf(s4[f][jf][j]);
            }
      }
      asm volatile("s_waitcnt lgkmcnt(0)" ::: "memory");
      __builtin_amdgcn_sched_barrier(0);
      short8 pf[2][2];
      #pragma unroll
      for (int f = 0; f < 2; ++f)
        #pragma unroll
        for (int kk = 0; kk < 2; ++kk)
          pf[f][kk] = *(const short8*)&((const u16*)Ks[cur])[
              (wid * 32 + f * 16 + l15) * 64 + ((kk * 32 + g * 8) ^ ((l15 & 7) << 3))];

      // ---- O += P V from Vt[cur] (vf read shared across both fragments)
      #pragma unroll
      for (int nf = 0; nf < 8; ++nf) {
        #pragma unroll
        for (int kk = 0; kk < 2; ++kk) {
          short8 vf = *(const short8*)&Vt[cur][(nf * 16 + l15) * PADV + kk * 32 + g * 8];
          o[0][nf] = mfma16(pf[0][kk], vf, o[0][nf]);
          o[1][nf] = mfma16(pf[1][kk], vf, o[1][nf]);
        }
      }

      // ---- late V stage: load+transpose-write just before the drain
      if (havenext) {
        const int kvn = (it + 1) * KBLK;
        const u16* vg = qkv + (rb + kvn + vk0) * LD3 + 2 * CC + h * DH + vd0;
        short8 r0 = *(const short8*)vg;
        short8 r1 = *(const short8*)(vg + LD3);
        short8 r2 = *(const short8*)(vg + 2 * LD3);
        short8 r3 = *(const short8*)(vg + 3 * LD3);
        #pragma unroll
        for (int j = 0; j < 8; ++j) {
          ushort4 w;
          w.x = (u16)r0[j]; w.y = (u16)r1[j]; w.z = (u16)r2[j]; w.w = (u16)r3[j];
          *(ushort4*)&Vt[nxt][(vd0 + j) * PADV + vk0] = w;
        }
      }
      asm volatile("s_waitcnt vmcnt(0)" ::: "memory");
      __syncthreads();
    }

    // ---- write back this q-tile
    #pragma unroll
    for (int f = 0; f < 2; ++f) {
      float inv[4];
      #pragma unroll
      for (int j = 0; j < 4; ++j) inv[j] = 1.0f / lrun[f][j];
      #pragma unroll
      for (int nf = 0; nf < 8; ++nf)
        #pragma unroll
        for (int j = 0; j < 4; ++j)
          y[(rb + qt0 + wid * 32 + f * 16 + 4 * g + j) * CC + h * DH + nf * 16 + l15] =
              f2bf(o[f][nf][j] * inv[j]);
    }
  }
}

// ------------------------------------------------------------------ launch
// Workspace layout: non-aliased, 193 MB total.
extern "C" void kernel_launch(void* const* d_in, const int* in_sizes, int n_in,
                              void* d_out, int out_size, void* d_ws, size_t ws_size,
                              hipStream_t stream) {
  const float* x = (const float*)d_in[0];
  const float* Wqkv = (const float*)d_in[1];
  const float* Wproj = (const float*)d_in[2];
  char* ws = (char*)d_ws;
  u16* xb     = (u16*)(ws);                      // 32 MB
  u16* wqkvT  = (u16*)(ws + 33554432);           // 24 MB
  u16* wprojT = (u16*)(ws + 58720256);           // 8 MB
  u16* qkv    = (u16*)(ws + 67108864);           // 96 MB
  u16* y      = (u16*)(ws + 167772160);          // 32 MB
  float2* tab = (float2*)(ws + 201326592);       // 1 MB

  convert_x_kernel<<<4096, 256, 0, stream>>>(x, xb);
  transpose_bf16_kernel<<<dim3(192, 64), dim3(32, 8), 0, stream>>>(Wqkv, wqkvT, CC, N3);
  transpose_bf16_kernel<<<dim3(64, 64), dim3(32, 8), 0, stream>>>(Wproj, wprojT, CC, CC);
  rope_table_kernel<<<512, 256, 0, stream>>>(tab);
  gemm_bt_256<<<dim3(24, 32), 512, 0, stream>>>(xb, wqkvT, (void*)qkv, CC, LD3, 1);
  rope_apply_kernel<<<8192, 256, 0, stream>>>(qkv, tab);
  attn_kernel<<<dim3(8, 64), 256, 0, stream>>>(qkv, y);
  gemm_bt_256<<<dim3(8, 32), 512, 0, stream>>>(y, wprojT, d_out, CC, CC, 0);
}

// Round 10
// 497.990 us; speedup vs baseline: 1.7753x; 1.0389x over previous
//
#include <hip/hip_runtime.h>

// Problem constants
#define BB 4
#define TT 2048
#define CC 2048
#define NHEAD 16
#define DH 128
#define MM (BB * TT)          // 8192 rows
#define N3 (3 * CC)           // 6144
#define LD3 6144

typedef unsigned short u16;
typedef __attribute__((ext_vector_type(8))) short short8;
typedef __attribute__((ext_vector_type(4))) float f32x4;

__device__ __forceinline__ u16 f2bf(float f) {
  unsigned u = __float_as_uint(f);
  u += 0x7fffu + ((u >> 16) & 1u);      // RNE
  return (u16)(u >> 16);
}
__device__ __forceinline__ float bf2f(u16 h) {
  return __uint_as_float(((unsigned)h) << 16);
}

__device__ __forceinline__ void gload_lds16(const void* g, void* l) {
  __builtin_amdgcn_global_load_lds((const __attribute__((address_space(1))) void*)g,
                                   (__attribute__((address_space(3))) void*)l, 16, 0, 0);
}

__device__ __forceinline__ f32x4 mfma16(short8 a, short8 b, f32x4 c) {
  return __builtin_amdgcn_mfma_f32_16x16x32_bf16(a, b, c, 0, 0, 0);
}

// ---------------------------------------------------------------- convert x
__global__ void convert_x_kernel(const float* __restrict__ x, u16* __restrict__ xb) {
  const int total = (MM * CC) / 4;
  const float4* xv = (const float4*)x;
  ushort4* ov = (ushort4*)xb;
  for (int i = blockIdx.x * blockDim.x + threadIdx.x; i < total; i += gridDim.x * blockDim.x) {
    float4 v = xv[i];
    ushort4 o;
    o.x = f2bf(v.x); o.y = f2bf(v.y); o.z = f2bf(v.z); o.w = f2bf(v.w);
    ov[i] = o;
  }
}

// ------------------------------------------- transpose + convert W -> W^T bf16
__global__ void transpose_bf16_kernel(const float* __restrict__ W, u16* __restrict__ Wt,
                                      int rows, int cols) {
  __shared__ float tile[32][33];
  const int n0 = blockIdx.x * 32, k0 = blockIdx.y * 32;
  const int tx = threadIdx.x, ty = threadIdx.y;   // (32, 8)
  #pragma unroll
  for (int i = 0; i < 4; ++i)
    tile[ty + 8 * i][tx] = W[(size_t)(k0 + ty + 8 * i) * cols + n0 + tx];
  __syncthreads();
  #pragma unroll
  for (int i = 0; i < 4; ++i)
    Wt[(size_t)(n0 + ty + 8 * i) * rows + k0 + tx] = f2bf(tile[tx][ty + 8 * i]);
}

// ---------------------------------------------------------------- rope table
__global__ void rope_table_kernel(float2* __restrict__ tab) {
  int idx = blockIdx.x * 256 + threadIdx.x;     // T*64 entries
  int t = idx >> 6, f = idx & 63;
  float freq = expf(-0.14391156831f * (float)f);   // 10000^(-f/64)
  float ang = (float)t * freq;
  float s, c;
  sincosf(ang, &s, &c);
  tab[idx] = make_float2(c, s);
}

// ------------------------------------------------------- rope apply (q and k)
// Vectorized: each thread rotates 8 contiguous freq pairs (short8 loads).
__global__ void rope_apply_kernel(u16* __restrict__ qkv, const float2* __restrict__ tab) {
  int idx = blockIdx.x * 256 + threadIdx.x;   // 2^21 = 2 * M * 16 * 8
  int f8 = idx & 7;
  int h = (idx >> 3) & 15;
  int m = (idx >> 7) & 8191;
  int which = idx >> 20;                      // 0 = q, 1 = k
  int t = m & (TT - 1);
  u16* p = qkv + (size_t)m * LD3 + which * CC + h * DH + f8 * 8;
  short8 v1 = *(const short8*)p;
  short8 v2 = *(const short8*)(p + 64);
  const float2* cs = &tab[(t << 6) + f8 * 8];
  const float scale = which ? 1.0f : 0.08838834764831845f;
  short8 o1, o2;
  #pragma unroll
  for (int j = 0; j < 8; ++j) {
    float2 c = cs[j];
    float x1 = bf2f((u16)v1[j]), x2 = bf2f((u16)v2[j]);
    o1[j] = (short)f2bf((x1 * c.x - x2 * c.y) * scale);
    o2[j] = (short)f2bf((x2 * c.x + x1 * c.y) * scale);
  }
  *(short8*)p = o1;
  *(short8*)(p + 64) = o2;
}

// ------------------------------------------------------------------- GEMM
// 256x256 tile, 8 waves (2M x 4N), BK=64. R10: fine per-phase interleave
// (m196/m201 lesson): per K-tile 4 phases, each = {quadrant ds_reads ||
// ONE stage chunk (2 gload_lds) ; s_barrier ; setprio+16 MFMA ;
// vmcnt(4)+s_barrier}. Chunk staged at phase q is published at end q+2,
// consumed q+3/q+4 (>=3-phase latency cover; never drains below 4 in-loop).
// swz47 LDS swizzle (R9: conflicts = 0), T1 XCD swizzle, T5 setprio.
#define TILE_B 32768   // bytes of one [256][64]-bf16 LDS tile

__device__ __forceinline__ int swz47(int x) { return x ^ (((x >> 7) & 7) << 4); }

__device__ __forceinline__ void stage_chunk(const u16* __restrict__ src, int K, int k0,
                                            char* ldsTile, int kind, int wid, int lane) {
  // kind: 0=A-q1rows 1=A-q3rows 2=B-lo 3=B-hi ; 2 loads/thread = 16KB chunk
  #pragma unroll
  for (int c = 0; c < 2; ++c) {
    int x;
    if (kind < 2) {
      x = (kind ? 8192 : 0) + c * 16384 + wid * 1024 + lane * 16;
    } else {
      int wl = wid * 2 + c;
      x = ((kind == 3) ? 4096 : 0) + (wl >> 2) * 8192 + (wl & 3) * 1024 + lane * 16;
    }
    int l = swz47(x);                      // logical byte (involution, row-preserving)
    int r = l >> 7;                        // row 0..255
    int ce = (l >> 1) & 63;                // col element 0..63 (16B-aligned)
    gload_lds16(src + (size_t)r * K + k0 + ce, ldsTile + (x - lane * 16));
  }
}

__global__ __launch_bounds__(512, 2) void gemm_bt_256(const u16* __restrict__ A,
                                                      const u16* __restrict__ Bt,
                                                      void* __restrict__ Cout,
                                                      int K, int ldc, int out_bf16) {
  __shared__ __align__(16) char As[2][TILE_B];
  __shared__ __align__(16) char Bs[2][TILE_B];
  const int tid = threadIdx.x;
  const int wid = tid >> 6, lane = tid & 63;
  const int l15 = lane & 15, g = lane >> 4;
  const int wr = wid >> 2, wc = wid & 3;          // 2M x 4N wave grid
  // T1 XCD swizzle (nwg % 8 == 0 for both call sites)
  const int nwg = gridDim.x * gridDim.y;
  const int orig = blockIdx.y * gridDim.x + blockIdx.x;
  const int swz = (orig & 7) * (nwg >> 3) + (orig >> 3);
  const int bx = swz % gridDim.x, by = swz / gridDim.x;
  const int row0 = by * 256, col0 = bx * 256;

  const u16* Ab = A + (size_t)row0 * K;
  const u16* Bb = Bt + (size_t)col0 * K;

  f32x4 acc[8][4];
  #pragma unroll
  for (int m = 0; m < 8; ++m)
    #pragma unroll
    for (int n = 0; n < 4; ++n) acc[m][n] = (f32x4){0.f, 0.f, 0.f, 0.f};

  // per-thread logical byte bases for fragment reads
  const int abase = (wr * 128 + l15) * 128 + g * 16;   // + m*2048 + ks*64
  const int bbase = (wc * 64 + l15) * 128 + g * 16;    // + n*2048 + ks*64

  // ---- prologue: tile 0 fully staged into buf 0
  stage_chunk(Ab, K, 0, As[0], 0, wid, lane);
  stage_chunk(Bb, K, 0, Bs[0], 2, wid, lane);
  stage_chunk(Bb, K, 0, Bs[0], 3, wid, lane);
  stage_chunk(Ab, K, 0, As[0], 1, wid, lane);
  asm volatile("s_waitcnt vmcnt(0)" ::: "memory");
  __builtin_amdgcn_s_barrier();

  const int nt = K >> 6;
  short8 a[4][2], blo[2][2], bhi[2][2];
  for (int kt = 0; kt < nt; ++kt) {
    const int cur = kt & 1, nx = cur ^ 1;
    const bool hn = (kt + 1) < nt;
    const int kn = (kt + 1) << 6;
    const char* At = As[cur];
    const char* Btl = Bs[cur];

    // ======== phase 1: q1 (m0-3 x n0-1) ; stage kind0 of tile kt+1
    #pragma unroll
    for (int m = 0; m < 4; ++m)
      #pragma unroll
      for (int ks = 0; ks < 2; ++ks)
        a[m][ks] = *(const short8*)(At + swz47(abase + m * 2048 + ks * 64));
    #pragma unroll
    for (int n = 0; n < 2; ++n)
      #pragma unroll
      for (int ks = 0; ks < 2; ++ks)
        blo[n][ks] = *(const short8*)(Btl + swz47(bbase + n * 2048 + ks * 64));
    if (hn) stage_chunk(Ab, K, kn, As[nx], 0, wid, lane);
    __builtin_amdgcn_s_barrier();
    __builtin_amdgcn_s_setprio(1);
    #pragma unroll
    for (int m = 0; m < 4; ++m)
      #pragma unroll
      for (int n = 0; n < 2; ++n)
        #pragma unroll
        for (int ks = 0; ks < 2; ++ks)
          acc[m][n] = mfma16(a[m][ks], blo[n][ks], acc[m][n]);
    __builtin_amdgcn_s_setprio(0);
    if (hn) asm volatile("s_waitcnt vmcnt(4)" ::: "memory");
    else    asm volatile("s_waitcnt vmcnt(2)" ::: "memory");
    __builtin_amdgcn_s_barrier();

    // ======== phase 2: q2 (m0-3 x n2-3) ; stage kind2 (B-lo) of tile kt+1
    #pragma unroll
    for (int n = 0; n < 2; ++n)
      #pragma unroll
      for (int ks = 0; ks < 2; ++ks)
        bhi[n][ks] = *(const short8*)(Btl + swz47(bbase + (n + 2) * 2048 + ks * 64));
    if (hn) stage_chunk(Bb, K, kn, Bs[nx], 2, wid, lane);
    __builtin_amdgcn_s_barrier();
    __builtin_amdgcn_s_setprio(1);
    #pragma unroll
    for (int m = 0; m < 4; ++m)
      #pragma unroll
      for (int n = 0; n < 2; ++n)
        #pragma unroll
        for (int ks = 0; ks < 2; ++ks)
          acc[m][n + 2] = mfma16(a[m][ks], bhi[n][ks], acc[m][n + 2]);
    __builtin_amdgcn_s_setprio(0);
    if (hn) asm volatile("s_waitcnt vmcnt(4)" ::: "memory");
    else    asm volatile("s_waitcnt vmcnt(0)" ::: "memory");
    __builtin_amdgcn_s_barrier();

    // ======== phase 3: q3 (m4-7 x n0-1) ; stage kind3 (B-hi) of tile kt+1
    #pragma unroll
    for (int m = 0; m < 4; ++m)
      #pragma unroll
      for (int ks = 0; ks < 2; ++ks)
        a[m][ks] = *(const short8*)(At + swz47(abase + (m + 4) * 2048 + ks * 64));
    if (hn) stage_chunk(Bb, K, kn, Bs[nx], 3, wid, lane);
    __builtin_amdgcn_s_barrier();
    __builtin_amdgcn_s_setprio(1);
    #pragma unroll
    for (int m = 0; m < 4; ++m)
      #pragma unroll
      for (int n = 0; n < 2; ++n)
        #pragma unroll
        for (int ks = 0; ks < 2; ++ks)
          acc[m + 4][n] = mfma16(a[m][ks], blo[n][ks], acc[m + 4][n]);
    __builtin_amdgcn_s_setprio(0);
    if (hn) asm volatile("s_waitcnt vmcnt(4)" ::: "memory");
    __builtin_amdgcn_s_barrier();

    // ======== phase 4: q4 (m4-7 x n2-3) ; stage kind1 (A-q3rows) of tile kt+1
    if (hn) stage_chunk(Ab, K, kn, As[nx], 1, wid, lane);
    __builtin_amdgcn_s_barrier();
    __builtin_amdgcn_s_setprio(1);
    #pragma unroll
    for (int m = 0; m < 4; ++m)
      #pragma unroll
      for (int n = 0; n < 2; ++n)
        #pragma unroll
        for (int ks = 0; ks < 2; ++ks)
          acc[m + 4][n + 2] = mfma16(a[m][ks], bhi[n][ks], acc[m + 4][n + 2]);
    __builtin_amdgcn_s_setprio(0);
    if (hn) asm volatile("s_waitcnt vmcnt(4)" ::: "memory");
    __builtin_amdgcn_s_barrier();
  }

  // ---- epilogue
  if (out_bf16) {
    u16* Cb = (u16*)Cout;
    #pragma unroll
    for (int m = 0; m < 8; ++m)
      #pragma unroll
      for (int n = 0; n < 4; ++n) {
        int row = row0 + wr * 128 + m * 16 + 4 * g;
        int col = col0 + wc * 64 + n * 16 + l15;
        #pragma unroll
        for (int j = 0; j < 4; ++j)
          Cb[(size_t)(row + j) * ldc + col] = f2bf(acc[m][n][j]);
      }
  } else {
    float* Cf = (float*)Cout;
    #pragma unroll
    for (int m = 0; m < 8; ++m)
      #pragma unroll
      for (int n = 0; n < 4; ++n) {
        int row = row0 + wr * 128 + m * 16 + 4 * g;
        int col = col0 + wc * 64 + n * 16 + l15;
        #pragma unroll
        for (int j = 0; j < 4; ++j)
          Cf[(size_t)(row + j) * ldc + col] = acc[m][n][j];
      }
  }
}

// ---------------------------------------------------------------- attention
// QBLK=128, diagonal pairing (uniform 34 iters/block), 512 blocks, 2 blocks/CU.
#define QBLK 128
#define KBLK 64
#define PADV 72

__global__ __launch_bounds__(256, 2) void attn_kernel(const u16* __restrict__ qkv,
                                                      u16* __restrict__ y) {
  __shared__ __align__(16) u16 Ks[2][KBLK * 128];   // K tile (swizzled) / P buffer
  __shared__ __align__(16) u16 Vt[2][DH * PADV];    // V^T [d][kv], padded
  const int tid = threadIdx.x;
  const int wid = tid >> 6, lane = tid & 63;
  const int l15 = lane & 15, g = lane >> 4;
  const int b = blockIdx.y >> 4, h = blockIdx.y & 15;
  const size_t rb = (size_t)b * TT;
  const int vk0 = (tid & 15) * 4, vd0 = (tid >> 4) * 8;   // V-staging assignment

  for (int half = 0; half < 2; ++half) {
    const int qt0 = (half ? (15 - (int)blockIdx.x) : (int)blockIdx.x) * QBLK;

    // ---- Q fragments straight from global (one-time; rows 12KB apart)
    short8 qf[2][4];
    {
      const u16* qbase = qkv + (rb + qt0 + wid * 32 + l15) * LD3 + h * DH;
      #pragma unroll
      for (int f = 0; f < 2; ++f)
        #pragma unroll
        for (int kk = 0; kk < 4; ++kk)
          qf[f][kk] = *(const short8*)(qbase + f * 16 * LD3 + kk * 32 + g * 8);
    }

    // ---- prologue: stage K(tile0) -> Ks[0], V(tile0) -> Vt[0]
    {
      const u16* kbase = qkv + (rb)*LD3 + CC + h * DH;
      #pragma unroll
      for (int c = 0; c < 4; ++c) {
        int chunk = c * 256 + tid;
        int r = chunk >> 4, s = chunk & 15;
        gload_lds16(kbase + (size_t)r * LD3 + (size_t)((s ^ (r & 7)) * 8),
                    &Ks[0][(c * 256 + wid * 64) * 8]);
      }
      const u16* vg = qkv + (rb + vk0) * LD3 + 2 * CC + h * DH + vd0;
      short8 r0 = *(const short8*)vg;
      short8 r1 = *(const short8*)(vg + LD3);
      short8 r2 = *(const short8*)(vg + 2 * LD3);
      short8 r3 = *(const short8*)(vg + 3 * LD3);
      #pragma unroll
      for (int j = 0; j < 8; ++j) {
        ushort4 w;
        w.x = (u16)r0[j]; w.y = (u16)r1[j]; w.z = (u16)r2[j]; w.w = (u16)r3[j];
        *(ushort4*)&Vt[0][(vd0 + j) * PADV + vk0] = w;
      }
    }
    asm volatile("s_waitcnt vmcnt(0)" ::: "memory");
    __syncthreads();

    f32x4 o[2][8];
    float mrun[2][4], lrun[2][4];
    #pragma unroll
    for (int f = 0; f < 2; ++f) {
      #pragma unroll
      for (int nf = 0; nf < 8; ++nf) o[f][nf] = (f32x4){0.f, 0.f, 0.f, 0.f};
      #pragma unroll
      for (int j = 0; j < 4; ++j) { mrun[f][j] = -1e30f; lrun[f][j] = 0.f; }
    }

    const int nt = qt0 / KBLK + 2;         // kv tiles (last two intersect diagonal)
    for (int it = 0; it < nt; ++it) {
      const int cur = it & 1, nxt = cur ^ 1;
      const bool havenext = (it + 1) < nt;
      if (havenext) {
        const int kvn = (it + 1) * KBLK;
        const u16* kbase = qkv + (rb + kvn) * LD3 + CC + h * DH;
        #pragma unroll
        for (int c = 0; c < 4; ++c) {
          int chunk = c * 256 + tid;
          int r = chunk >> 4, s = chunk & 15;
          gload_lds16(kbase + (size_t)r * LD3 + (size_t)((s ^ (r & 7)) * 8),
                      &Ks[nxt][(c * 256 + wid * 64) * 8]);
        }
      }

      // ---- S = Q K^T from Ks[cur] (q pre-scaled by 1/sqrt(D))
      f32x4 s4[2][4];
      #pragma unroll
      for (int f = 0; f < 2; ++f)
        #pragma unroll
        for (int jf = 0; jf < 4; ++jf) s4[f][jf] = (f32x4){0.f, 0.f, 0.f, 0.f};
      #pragma unroll
      for (int jf = 0; jf < 4; ++jf) {
        int krow = jf * 16 + l15;
        #pragma unroll
        for (int kk = 0; kk < 4; ++kk) {
          short8 kf = *(const short8*)((const char*)Ks[cur] + krow * 256 +
                                       ((kk * 64 + g * 16) ^ ((l15 & 7) << 4)));
          s4[0][jf] = mfma16(qf[0][kk], kf, s4[0][jf]);
          s4[1][jf] = mfma16(qf[1][kk], kf, s4[1][jf]);
        }
      }
      // causal mask: last two tiles intersect the diagonal of this q-block
      if (it >= nt - 2) {
        const int kvb = it * KBLK - qt0;   // kv offset relative to q-block base
        #pragma unroll
        for (int f = 0; f < 2; ++f)
          #pragma unroll
          for (int jf = 0; jf < 4; ++jf)
            #pragma unroll
            for (int j = 0; j < 4; ++j)
              if (kvb + jf * 16 + l15 > wid * 32 + f * 16 + 4 * g + j)
                s4[f][jf][j] = -1e30f;
      }
      // ---- online softmax per fragment
      #pragma unroll
      for (int f = 0; f < 2; ++f) {
        float rmax[4], corr[4], rsum[4];
        #pragma unroll
        for (int j = 0; j < 4; ++j)
          rmax[j] = fmaxf(fmaxf(s4[f][0][j], s4[f][1][j]), fmaxf(s4[f][2][j], s4[f][3][j]));
        #pragma unroll
        for (int j = 0; j < 4; ++j) {
          rmax[j] = fmaxf(rmax[j], __shfl_xor(rmax[j], 1, 64));
          rmax[j] = fmaxf(rmax[j], __shfl_xor(rmax[j], 2, 64));
          rmax[j] = fmaxf(rmax[j], __shfl_xor(rmax[j], 4, 64));
          rmax[j] = fmaxf(rmax[j], __shfl_xor(rmax[j], 8, 64));
        }
        #pragma unroll
        for (int j = 0; j < 4; ++j) {
          float mn = fmaxf(mrun[f][j], rmax[j]);
          corr[j] = __expf(mrun[f][j] - mn);
          mrun[f][j] = mn;
        }
        #pragma unroll
        for (int jf = 0; jf < 4; ++jf)
          #pragma unroll
          for (int j = 0; j < 4; ++j)
            s4[f][jf][j] = __expf(s4[f][jf][j] - mrun[f][j]);
        #pragma unroll
        for (int j = 0; j < 4; ++j) {
          rsum[j] = (s4[f][0][j] + s4[f][1][j]) + (s4[f][2][j] + s4[f][3][j]);
          rsum[j] += __shfl_xor(rsum[j], 1, 64);
          rsum[j] += __shfl_xor(rsum[j], 2, 64);
          rsum[j] += __shfl_xor(rsum[j], 4, 64);
          rsum[j] += __shfl_xor(rsum[j], 8, 64);
          lrun[f][j] = lrun[f][j] * corr[j] + rsum[j];
        }
        #pragma unroll
        for (int nf = 0; nf < 8; ++nf)
          #pragma unroll
          for (int j = 0; j < 4; ++j)
            o[f][nf][j] *= corr[j];
      }

      // ---- all waves done reading K from Ks[cur]; reuse it as the P buffer
      __syncthreads();
      // P flat [128 q-rows][64 kv], G4 XOR swizzle: col ^= (row&7)<<3
      {
        u16* Pb = (u16*)Ks[cur];
        #pragma unroll
        for (int f = 0; f < 2; ++f)
          #pragma unroll
          for (int jf = 0; jf < 4; ++jf)
            #pragma unroll
            for (int j = 0; j < 4; ++j) {
              int prow = wid * 32 + f * 16 + 4 * g + j;
              int pcol = (jf * 16 + l15) ^ (((4 * g + j) & 7) << 3);
              Pb[prow * 64 + pcol] = f2bf(s4[f][jf][j]);
            }
      }
      asm volatile("s_waitcnt lgkmcnt(0)" ::: "memory");
      __builtin_amdgcn_sched_barrier(0);
      short8 pf[2][2];
      #pragma unroll
      for (int f = 0; f < 2; ++f)
        #pragma unroll
        for (int kk = 0; kk < 2; ++kk)
          pf[f][kk] = *(const short8*)&((const u16*)Ks[cur])[
              (wid * 32 + f * 16 + l15) * 64 + ((kk * 32 + g * 8) ^ ((l15 & 7) << 3))];

      // ---- O += P V from Vt[cur] (vf read shared across both fragments)
      #pragma unroll
      for (int nf = 0; nf < 8; ++nf) {
        #pragma unroll
        for (int kk = 0; kk < 2; ++kk) {
          short8 vf = *(const short8*)&Vt[cur][(nf * 16 + l15) * PADV + kk * 32 + g * 8];
          o[0][nf] = mfma16(pf[0][kk], vf, o[0][nf]);
          o[1][nf] = mfma16(pf[1][kk], vf, o[1][nf]);
        }
      }

      // ---- late V stage: load+transpose-write just before the drain
      if (havenext) {
        const int kvn = (it + 1) * KBLK;
        const u16* vg = qkv + (rb + kvn + vk0) * LD3 + 2 * CC + h * DH + vd0;
        short8 r0 = *(const short8*)vg;
        short8 r1 = *(const short8*)(vg + LD3);
        short8 r2 = *(const short8*)(vg + 2 * LD3);
        short8 r3 = *(const short8*)(vg + 3 * LD3);
        #pragma unroll
        for (int j = 0; j < 8; ++j) {
          ushort4 w;
          w.x = (u16)r0[j]; w.y = (u16)r1[j]; w.z = (u16)r2[j]; w.w = (u16)r3[j];
          *(ushort4*)&Vt[nxt][(vd0 + j) * PADV + vk0] = w;
        }
      }
      asm volatile("s_waitcnt vmcnt(0)" ::: "memory");
      __syncthreads();
    }

    // ---- write back this q-tile
    #pragma unroll
    for (int f = 0; f < 2; ++f) {
      float inv[4];
      #pragma unroll
      for (int j = 0; j < 4; ++j) inv[j] = 1.0f / lrun[f][j];
      #pragma unroll
      for (int nf = 0; nf < 8; ++nf)
        #pragma unroll
        for (int j = 0; j < 4; ++j)
          y[(rb + qt0 + wid * 32 + f * 16 + 4 * g + j) * CC + h * DH + nf * 16 + l15] =
              f2bf(o[f][nf][j] * inv[j]);
    }
  }
}

// ------------------------------------------------------------------ launch
// Workspace layout: non-aliased, 193 MB total.
extern "C" void kernel_launch(void* const* d_in, const int* in_sizes, int n_in,
                              void* d_out, int out_size, void* d_ws, size_t ws_size,
                              hipStream_t stream) {
  const float* x = (const float*)d_in[0];
  const float* Wqkv = (const float*)d_in[1];
  const float* Wproj = (const float*)d_in[2];
  char* ws = (char*)d_ws;
  u16* xb     = (u16*)(ws);                      // 32 MB
  u16* wqkvT  = (u16*)(ws + 33554432);           // 24 MB
  u16* wprojT = (u16*)(ws + 58720256);           // 8 MB
  u16* qkv    = (u16*)(ws + 67108864);           // 96 MB
  u16* y      = (u16*)(ws + 167772160);          // 32 MB
  float2* tab = (float2*)(ws + 201326592);       // 1 MB

  convert_x_kernel<<<4096, 256, 0, stream>>>(x, xb);
  transpose_bf16_kernel<<<dim3(192, 64), dim3(32, 8), 0, stream>>>(Wqkv, wqkvT, CC, N3);
  transpose_bf16_kernel<<<dim3(64, 64), dim3(32, 8), 0, stream>>>(Wproj, wprojT, CC, CC);
  rope_table_kernel<<<512, 256, 0, stream>>>(tab);
  gemm_bt_256<<<dim3(24, 32), 512, 0, stream>>>(xb, wqkvT, (void*)qkv, CC, LD3, 1);
  rope_apply_kernel<<<8192, 256, 0, stream>>>(qkv, tab);
  attn_kernel<<<dim3(8, 64), 256, 0, stream>>>(qkv, y);
  gemm_bt_256<<<dim3(8, 32), 512, 0, stream>>>(y, wprojT, d_out, CC, CC, 0);
}